// Round 1
// baseline (414.068 us; speedup 1.0000x reference)
//
#include <hip/hip_runtime.h>
#include <math.h>

#define T_TOK 4096
#define HDIM  1024
#define NEXP  16
#define IDIM  512
#define ISHD  1024

typedef unsigned int u32;
typedef unsigned short u16;
typedef __attribute__((ext_vector_type(8))) short bfrag;   // 8 bf16 (4 VGPRs)
typedef __attribute__((ext_vector_type(4))) float f32x4;

__device__ __forceinline__ u16 f2bf(float f) {
    union { float f; u32 u; } c; c.f = f;
    u32 u = c.u;
    u32 r = u + 0x7fffu + ((u >> 16) & 1u);   // RNE
    return (u16)(r >> 16);
}
__device__ __forceinline__ float bf2f(u16 h) {
    union { u32 u; float f; } c; c.u = ((u32)h) << 16;
    return c.f;
}

__device__ __forceinline__ void async16(void* lds, const void* g) {
    __builtin_amdgcn_global_load_lds((__attribute__((address_space(1))) void*)(g),
                                     (__attribute__((address_space(3))) void*)(lds),
                                     16, 0, 0);
}

// ---------------- f32 -> bf16 convert (x) ----------------
__global__ __launch_bounds__(256) void cvt_f32_bf16(const float* __restrict__ src,
                                                    u16* __restrict__ dst, int n) {
    int i = (blockIdx.x * 256 + threadIdx.x) * 4;
    if (i >= n) return;
    float4 v = *(const float4*)(src + i);
    ushort4 o;
    o.x = f2bf(v.x); o.y = f2bf(v.y); o.z = f2bf(v.z); o.w = f2bf(v.w);
    *(ushort4*)(dst + i) = o;
}

// ---------------- transpose f32 [R][C] -> bf16 [C][R], batched ----------------
__global__ __launch_bounds__(256) void transpose_k(const float* __restrict__ src,
                                                   u16* __restrict__ dst,
                                                   int R, int C, long bstride) {
    __shared__ float tile[32][33];
    long base = (long)blockIdx.z * bstride;
    int c0 = blockIdx.x * 32, r0 = blockIdx.y * 32;
    int tx = threadIdx.x, ty = threadIdx.y;   // (32, 8)
#pragma unroll
    for (int j = 0; j < 4; ++j)
        tile[ty + 8 * j][tx] = src[base + (long)(r0 + ty + 8 * j) * C + (c0 + tx)];
    __syncthreads();
#pragma unroll
    for (int j = 0; j < 4; ++j)
        dst[base + (long)(c0 + ty + 8 * j) * R + (r0 + tx)] = f2bf(tile[tx][ty + 8 * j]);
}

// ---------------- router: sigmoid scores, top-2, normalized weights ----------------
__global__ __launch_bounds__(256) void router_k(const float* __restrict__ x,
                                                const float* __restrict__ rw,
                                                const float* __restrict__ bias,
                                                int* __restrict__ sel,
                                                float* __restrict__ wts,
                                                int* __restrict__ counts) {
    int t = blockIdx.x;
    const float* xr = x + (long)t * HDIM;
    int tid = threadIdx.x;
    int e = tid & 15, c = tid >> 4;
    float p = 0.f;
    int h0 = c * 64;
    for (int h = 0; h < 64; ++h) p += xr[h0 + h] * rw[(long)(h0 + h) * NEXP + e];
    __shared__ float red[256];
    red[tid] = p;
    __syncthreads();
    for (int s = 128; s >= 16; s >>= 1) {
        if (tid < s) red[tid] += red[tid + s];
        __syncthreads();
    }
    if (tid == 0) {
        float sc[NEXP];
        for (int j = 0; j < NEXP; ++j) sc[j] = 1.f / (1.f + expf(-red[j]));
        int i0 = -1, i1 = -1; float v0 = -1e30f, v1 = -1e30f;
        for (int j = 0; j < NEXP; ++j) {
            float v = sc[j] + bias[j];
            if (v > v0) { v1 = v0; i1 = i0; v0 = v; i0 = j; }
            else if (v > v1) { v1 = v; i1 = j; }
        }
        float s0 = sc[i0], s1 = sc[i1];
        float nrm = s0 + s1 + 1e-20f;
        sel[t * 2] = i0; sel[t * 2 + 1] = i1;
        wts[t * 2] = s0 / nrm; wts[t * 2 + 1] = s1 / nrm;
        atomicAdd(&counts[i0], 1); atomicAdd(&counts[i1], 1);
    }
}

__global__ void prefix_k(const int* __restrict__ counts, int* __restrict__ offs,
                         int* __restrict__ cursors) {
    if (threadIdx.x == 0 && blockIdx.x == 0) {
        int a = 0;
        for (int e = 0; e < NEXP; ++e) { offs[e] = a; cursors[e] = a; a += counts[e]; }
        offs[NEXP] = a;
    }
}

__global__ __launch_bounds__(256) void build_k(const int* __restrict__ sel,
                                               int* __restrict__ cursors,
                                               int* __restrict__ rowmap,
                                               int* __restrict__ invmap) {
    int t = blockIdx.x * 256 + threadIdx.x;
    if (t >= T_TOK) return;
    for (int k = 0; k < 2; ++k) {
        int e = sel[t * 2 + k];
        int slot = atomicAdd(&cursors[e], 1);
        rowmap[slot] = t;
        invmap[t * 2 + k] = slot;
    }
}

// ---------------- MFMA GEMM: C[M,N] = A[M,K](bf16) @ Bt[N,K]^T(bf16) ----------------
// EPI 0: store f32. EPI 1: read Gbuf(f32), store bf16 silu(g)*acc. EPI 2: store bf16.
// offs != null: per-expert row range [offs[e], offs[e+1]) (blockIdx.z = expert).
// rowmap != null: A-row gather through rowmap.
template<int EPI>
__global__ __launch_bounds__(256)
void gemm_tile(const u16* __restrict__ A, int lda,
               const u16* __restrict__ Bt, long strideBt,
               void* __restrict__ Cptr, const float* __restrict__ Gbuf, int ldc,
               int M, int N, int K,
               const int* __restrict__ offs, const int* __restrict__ rowmap) {
    int e = blockIdx.z;
    int moff = 0, mend = M;
    if (offs) { moff = offs[e]; mend = offs[e + 1]; }
    int row0 = moff + blockIdx.y * 128;
    if (row0 >= mend) return;
    int col0 = blockIdx.x * 128;
    const u16* B = Bt + (long)e * strideBt;

    __shared__ u16 sA[128 * 64];
    __shared__ u16 sB[128 * 64];

    int tid = threadIdx.x;
    int lane = tid & 63;
    int w = tid >> 6;
    int wr = (w >> 1) * 64, wc = (w & 1) * 64;
    int lhi = lane >> 4, llo = lane & 15;

    f32x4 acc[4][4];
#pragma unroll
    for (int m = 0; m < 4; ++m)
#pragma unroll
        for (int n = 0; n < 4; ++n) { f32x4 z = {0.f, 0.f, 0.f, 0.f}; acc[m][n] = z; }

    for (int k0 = 0; k0 < K; k0 += 64) {
#pragma unroll
        for (int c = 0; c < 4; ++c) {
            int idx = c * 256 + tid;          // 0..1023
            int r = idx >> 3, ch = idx & 7;   // row-in-tile, 16B chunk
            int grow = row0 + r;
            int sgrow = (grow < mend) ? grow : moff;
            int arow = rowmap ? rowmap[sgrow] : sgrow;
            async16(&sA[idx * 8], &A[(long)arow * lda + k0 + ch * 8]);
            async16(&sB[idx * 8], &B[(long)(col0 + r) * K + k0 + ch * 8]);
        }
        __syncthreads();
#pragma unroll
        for (int kk = 0; kk < 2; ++kk) {
            bfrag a[4], b[4];
#pragma unroll
            for (int m = 0; m < 4; ++m)
                a[m] = *(const bfrag*)&sA[(wr + m * 16 + llo) * 64 + kk * 32 + lhi * 8];
#pragma unroll
            for (int n = 0; n < 4; ++n)
                b[n] = *(const bfrag*)&sB[(wc + n * 16 + llo) * 64 + kk * 32 + lhi * 8];
#pragma unroll
            for (int m = 0; m < 4; ++m)
#pragma unroll
                for (int n = 0; n < 4; ++n)
                    acc[m][n] = __builtin_amdgcn_mfma_f32_16x16x32_bf16(a[m], b[n], acc[m][n], 0, 0, 0);
        }
        __syncthreads();
    }

    float* Cf = (float*)Cptr;
    u16* Cb = (u16*)Cptr;
#pragma unroll
    for (int m = 0; m < 4; ++m) {
        int rbase = row0 + wr + m * 16 + lhi * 4;
#pragma unroll
        for (int n = 0; n < 4; ++n) {
            int gcol = col0 + wc + n * 16 + llo;
#pragma unroll
            for (int i = 0; i < 4; ++i) {
                int grow = rbase + i;
                if (grow >= mend) continue;
                long off = (long)grow * ldc + gcol;
                float v = acc[m][n][i];
                if (EPI == 0) {
                    Cf[off] = v;
                } else if (EPI == 1) {
                    float g = Gbuf[off];
                    float s = g / (1.f + expf(-g));
                    Cb[off] = f2bf(s * v);
                } else {
                    Cb[off] = f2bf(v);
                }
            }
        }
    }
}

// ---------------- combine: out[t] += w0*eo[r0] + w1*eo[r1] ----------------
__global__ __launch_bounds__(256) void combine_k(float* __restrict__ out,
                                                 const u16* __restrict__ eo,
                                                 const int* __restrict__ invmap,
                                                 const float* __restrict__ wts) {
    int t = blockIdx.x;
    int h = threadIdx.x * 4;
    int r0 = invmap[t * 2], r1 = invmap[t * 2 + 1];
    float w0 = wts[t * 2], w1 = wts[t * 2 + 1];
    float* op = out + (long)t * HDIM + h;
    float4 o = *(float4*)op;
    ushort4 a = *(const ushort4*)(eo + (long)r0 * HDIM + h);
    ushort4 b = *(const ushort4*)(eo + (long)r1 * HDIM + h);
    o.x += w0 * bf2f(a.x) + w1 * bf2f(b.x);
    o.y += w0 * bf2f(a.y) + w1 * bf2f(b.y);
    o.z += w0 * bf2f(a.z) + w1 * bf2f(b.z);
    o.w += w0 * bf2f(a.w) + w1 * bf2f(b.w);
    *(float4*)op = o;
}

extern "C" void kernel_launch(void* const* d_in, const int* in_sizes, int n_in,
                              void* d_out, int out_size, void* d_ws, size_t ws_size,
                              hipStream_t stream) {
    const float* x    = (const float*)d_in[0];
    const float* rw   = (const float*)d_in[1];
    const float* bias = (const float*)d_in[2];
    const float* wg   = (const float*)d_in[3];
    const float* wu   = (const float*)d_in[4];
    const float* wd   = (const float*)d_in[5];
    const float* swg  = (const float*)d_in[6];
    const float* swu  = (const float*)d_in[7];
    const float* swd  = (const float*)d_in[8];
    float* out = (float*)d_out;

    char* ws = (char*)d_ws;
    size_t o = 0;
    auto alloc = [&](size_t bytes) -> void* {
        void* p = ws + o;
        o += (bytes + 255) & ~(size_t)255;
        return p;
    };
    u16* x_bf = (u16*)alloc((size_t)T_TOK * HDIM * 2);
    u16* WtG  = (u16*)alloc((size_t)NEXP * IDIM * HDIM * 2);
    u16* WtU  = (u16*)alloc((size_t)NEXP * IDIM * HDIM * 2);
    u16* WtD  = (u16*)alloc((size_t)NEXP * HDIM * IDIM * 2);
    u16* SWtG = (u16*)alloc((size_t)ISHD * HDIM * 2);
    u16* SWtU = (u16*)alloc((size_t)ISHD * HDIM * 2);
    u16* SWtD = (u16*)alloc((size_t)HDIM * ISHD * 2);
    void* P1  = alloc(16777216);   // shared-g f32 [4096][1024] / routed-g f32 [8192][512] / eo bf16 [8192][1024]
    void* P2  = alloc(8388608);    // h1 bf16 [4096][1024] / a_r bf16 [8192][512]
    int*   sel     = (int*)alloc((size_t)T_TOK * 2 * 4);
    float* wts     = (float*)alloc((size_t)T_TOK * 2 * 4);
    int*   invmap  = (int*)alloc((size_t)T_TOK * 2 * 4);
    int*   rowmap  = (int*)alloc((size_t)T_TOK * 2 * 4);
    int*   counts  = (int*)alloc(64);
    int*   offs    = (int*)alloc(128);
    int*   cursors = (int*)alloc(64);

    hipMemsetAsync(counts, 0, 64, stream);

    cvt_f32_bf16<<<dim3((T_TOK * HDIM) / (4 * 256)), 256, 0, stream>>>(x, x_bf, T_TOK * HDIM);

    transpose_k<<<dim3(IDIM / 32, HDIM / 32, NEXP), dim3(32, 8), 0, stream>>>(wg, WtG, HDIM, IDIM, (long)HDIM * IDIM);
    transpose_k<<<dim3(IDIM / 32, HDIM / 32, NEXP), dim3(32, 8), 0, stream>>>(wu, WtU, HDIM, IDIM, (long)HDIM * IDIM);
    transpose_k<<<dim3(HDIM / 32, IDIM / 32, NEXP), dim3(32, 8), 0, stream>>>(wd, WtD, IDIM, HDIM, (long)IDIM * HDIM);
    transpose_k<<<dim3(ISHD / 32, HDIM / 32, 1), dim3(32, 8), 0, stream>>>(swg, SWtG, HDIM, ISHD, (long)HDIM * ISHD);
    transpose_k<<<dim3(ISHD / 32, HDIM / 32, 1), dim3(32, 8), 0, stream>>>(swu, SWtU, HDIM, ISHD, (long)HDIM * ISHD);
    transpose_k<<<dim3(HDIM / 32, ISHD / 32, 1), dim3(32, 8), 0, stream>>>(swd, SWtD, ISHD, HDIM, (long)ISHD * HDIM);

    router_k<<<dim3(T_TOK), 256, 0, stream>>>(x, rw, bias, sel, wts, counts);
    prefix_k<<<dim3(1), 64, 0, stream>>>(counts, offs, cursors);
    build_k<<<dim3(T_TOK / 256), 256, 0, stream>>>(sel, cursors, rowmap, invmap);

    float* gS = (float*)P1;
    u16*   h1 = (u16*)P2;
    float* gR = (float*)P1;
    u16*   aR = (u16*)P2;
    u16*   eo = (u16*)P1;

    // shared expert: g = x@swg ; h1 = silu(g)*(x@swu) ; out = h1@swd
    gemm_tile<0><<<dim3(ISHD / 128, T_TOK / 128, 1), 256, 0, stream>>>(
        x_bf, HDIM, SWtG, 0, gS, nullptr, ISHD, T_TOK, ISHD, HDIM, nullptr, nullptr);
    gemm_tile<1><<<dim3(ISHD / 128, T_TOK / 128, 1), 256, 0, stream>>>(
        x_bf, HDIM, SWtU, 0, h1, gS, ISHD, T_TOK, ISHD, HDIM, nullptr, nullptr);
    gemm_tile<0><<<dim3(HDIM / 128, T_TOK / 128, 1), 256, 0, stream>>>(
        h1, ISHD, SWtD, 0, out, nullptr, HDIM, T_TOK, HDIM, ISHD, nullptr, nullptr);

    // routed experts: gathered rows per expert
    gemm_tile<0><<<dim3(IDIM / 128, T_TOK / 128, NEXP), 256, 0, stream>>>(
        x_bf, HDIM, WtG, (long)IDIM * HDIM, gR, nullptr, IDIM, T_TOK, IDIM, HDIM, offs, rowmap);
    gemm_tile<1><<<dim3(IDIM / 128, T_TOK / 128, NEXP), 256, 0, stream>>>(
        x_bf, HDIM, WtU, (long)IDIM * HDIM, aR, gR, IDIM, T_TOK, IDIM, HDIM, offs, rowmap);
    gemm_tile<2><<<dim3(HDIM / 128, T_TOK / 128, NEXP), 256, 0, stream>>>(
        aR, IDIM, WtD, (long)HDIM * IDIM, eo, nullptr, HDIM, T_TOK, HDIM, IDIM, offs, nullptr);

    combine_k<<<dim3(T_TOK), 256, 0, stream>>>(out, eo, invmap, wts);
}

// Round 2
// 411.923 us; speedup vs baseline: 1.0052x; 1.0052x over previous
//
#include <hip/hip_runtime.h>
#include <math.h>

#define T_TOK 4096
#define HDIM  1024
#define NEXP  16
#define IDIM  512
#define ISHD  1024

typedef unsigned int u32;
typedef unsigned short u16;
typedef __attribute__((ext_vector_type(8))) short bfrag;   // 8 bf16 (4 VGPRs)
typedef __attribute__((ext_vector_type(4))) float f32x4;

__device__ __forceinline__ u16 f2bf(float f) {
    union { float f; u32 u; } c; c.f = f;
    u32 u = c.u;
    u32 r = u + 0x7fffu + ((u >> 16) & 1u);   // RNE
    return (u16)(r >> 16);
}
__device__ __forceinline__ float bf2f(u16 h) {
    union { u32 u; float f; } c; c.u = ((u32)h) << 16;
    return c.f;
}

__device__ __forceinline__ void async16(void* lds, const void* g) {
    __builtin_amdgcn_global_load_lds((__attribute__((address_space(1))) void*)(g),
                                     (__attribute__((address_space(3))) void*)(lds),
                                     16, 0, 0);
}

// ---------------- f32 -> bf16 convert (x) ----------------
__global__ __launch_bounds__(256) void cvt_f32_bf16(const float* __restrict__ src,
                                                    u16* __restrict__ dst, int n) {
    int i = (blockIdx.x * 256 + threadIdx.x) * 4;
    if (i >= n) return;
    float4 v = *(const float4*)(src + i);
    ushort4 o;
    o.x = f2bf(v.x); o.y = f2bf(v.y); o.z = f2bf(v.z); o.w = f2bf(v.w);
    *(ushort4*)(dst + i) = o;
}

// ---------------- transpose f32 [R][C] -> bf16 [C][R], batched ----------------
__global__ __launch_bounds__(256) void transpose_k(const float* __restrict__ src,
                                                   u16* __restrict__ dst,
                                                   int R, int C, long bstride) {
    __shared__ float tile[32][33];
    long base = (long)blockIdx.z * bstride;
    int c0 = blockIdx.x * 32, r0 = blockIdx.y * 32;
    int tx = threadIdx.x, ty = threadIdx.y;   // (32, 8)
#pragma unroll
    for (int j = 0; j < 4; ++j)
        tile[ty + 8 * j][tx] = src[base + (long)(r0 + ty + 8 * j) * C + (c0 + tx)];
    __syncthreads();
#pragma unroll
    for (int j = 0; j < 4; ++j)
        dst[base + (long)(c0 + ty + 8 * j) * R + (r0 + tx)] = f2bf(tile[tx][ty + 8 * j]);
}

// ---------------- router v2: one wave per token ----------------
// lane = (e = lane&15, hc = lane>>4). Each lane: 256-long dot (float4 x).
// shfl_down folds the 4 h-chunks; all-lane shfl top-2 scan; lane 0 writes.
__global__ __launch_bounds__(256) void router_k(const float* __restrict__ x,
                                                const float* __restrict__ rw,
                                                const float* __restrict__ bias,
                                                int* __restrict__ sel,
                                                float* __restrict__ wts,
                                                int* __restrict__ counts) {
    int tid = threadIdx.x;
    int wv = tid >> 6;
    int lane = tid & 63;
    int t = blockIdx.x * 4 + wv;
    int e = lane & 15, hc = lane >> 4;
    const float* xr = x + (long)t * HDIM + hc * 256;
    const float* rp = rw + (long)hc * 256 * NEXP + e;
    float acc = 0.f;
#pragma unroll 4
    for (int i = 0; i < 64; ++i) {
        float4 xv = *(const float4*)(xr + i * 4);
        acc += xv.x * rp[(i * 4 + 0) * NEXP] + xv.y * rp[(i * 4 + 1) * NEXP]
             + xv.z * rp[(i * 4 + 2) * NEXP] + xv.w * rp[(i * 4 + 3) * NEXP];
    }
    acc += __shfl_down(acc, 16);
    acc += __shfl_down(acc, 32);
    float sc = 1.f / (1.f + expf(-acc));       // valid on lanes 0..15
    float v = sc + bias[e];
    int i0 = -1, i1 = -1;
    float v0 = -1e30f, v1 = -1e30f, s0 = 0.f, s1 = 0.f;
#pragma unroll
    for (int j = 0; j < 16; ++j) {
        float vj = __shfl(v, j);
        float scj = __shfl(sc, j);
        if (vj > v0) { v1 = v0; i1 = i0; s1 = s0; v0 = vj; i0 = j; s0 = scj; }
        else if (vj > v1) { v1 = vj; i1 = j; s1 = scj; }
    }
    if (lane == 0) {
        float nrm = s0 + s1 + 1e-20f;
        sel[t * 2] = i0; sel[t * 2 + 1] = i1;
        wts[t * 2] = s0 / nrm; wts[t * 2 + 1] = s1 / nrm;
        atomicAdd(&counts[i0], 1); atomicAdd(&counts[i1], 1);
    }
}

__global__ void prefix_k(const int* __restrict__ counts, int* __restrict__ offs,
                         int* __restrict__ cursors) {
    if (threadIdx.x == 0 && blockIdx.x == 0) {
        int a = 0;
        for (int e = 0; e < NEXP; ++e) { offs[e] = a; cursors[e] = a; a += counts[e]; }
        offs[NEXP] = a;
    }
}

__global__ __launch_bounds__(256) void build_k(const int* __restrict__ sel,
                                               int* __restrict__ cursors,
                                               int* __restrict__ rowmap,
                                               int* __restrict__ invmap) {
    int t = blockIdx.x * 256 + threadIdx.x;
    if (t >= T_TOK) return;
    for (int k = 0; k < 2; ++k) {
        int e = sel[t * 2 + k];
        int slot = atomicAdd(&cursors[e], 1);
        rowmap[slot] = t;
        invmap[t * 2 + k] = slot;
    }
}

// ---------------- MFMA GEMM: C[M,N] = A[M,K](bf16) @ Bt[N,K]^T(bf16) ----------------
// EPI 0: store f32. EPI 1: read Gbuf(bf16 = silu(g)), store bf16 g*acc.
// EPI 2: store bf16. EPI 3: store bf16 silu(acc).
// offs != null: per-expert row range [offs[e], offs[e+1]) (blockIdx.z = expert).
// rowmap != null: A-row gather through rowmap.
template<int EPI>
__global__ __launch_bounds__(256)
void gemm_tile(const u16* __restrict__ A, int lda,
               const u16* __restrict__ Bt, long strideBt,
               void* __restrict__ Cptr, const u16* __restrict__ Gbuf, int ldc,
               int M, int N, int K,
               const int* __restrict__ offs, const int* __restrict__ rowmap) {
    int e = blockIdx.z;
    int moff = 0, mend = M;
    if (offs) { moff = offs[e]; mend = offs[e + 1]; }
    int row0 = moff + blockIdx.y * 128;
    if (row0 >= mend) return;
    int col0 = blockIdx.x * 128;
    const u16* B = Bt + (long)e * strideBt;

    __shared__ u16 sA[128 * 64];
    __shared__ u16 sB[128 * 64];

    int tid = threadIdx.x;
    int lane = tid & 63;
    int w = tid >> 6;
    int wr = (w >> 1) * 64, wc = (w & 1) * 64;
    int lhi = lane >> 4, llo = lane & 15;

    f32x4 acc[4][4];
#pragma unroll
    for (int m = 0; m < 4; ++m)
#pragma unroll
        for (int n = 0; n < 4; ++n) { f32x4 z = {0.f, 0.f, 0.f, 0.f}; acc[m][n] = z; }

    for (int k0 = 0; k0 < K; k0 += 64) {
#pragma unroll
        for (int c = 0; c < 4; ++c) {
            int idx = c * 256 + tid;          // 0..1023
            int r = idx >> 3, ch = idx & 7;   // row-in-tile, 16B chunk
            int grow = row0 + r;
            int sgrow = (grow < mend) ? grow : moff;
            int arow = rowmap ? rowmap[sgrow] : sgrow;
            async16(&sA[idx * 8], &A[(long)arow * lda + k0 + ch * 8]);
            async16(&sB[idx * 8], &B[(long)(col0 + r) * K + k0 + ch * 8]);
        }
        __syncthreads();
#pragma unroll
        for (int kk = 0; kk < 2; ++kk) {
            bfrag a[4], b[4];
#pragma unroll
            for (int m = 0; m < 4; ++m)
                a[m] = *(const bfrag*)&sA[(wr + m * 16 + llo) * 64 + kk * 32 + lhi * 8];
#pragma unroll
            for (int n = 0; n < 4; ++n)
                b[n] = *(const bfrag*)&sB[(wc + n * 16 + llo) * 64 + kk * 32 + lhi * 8];
#pragma unroll
            for (int m = 0; m < 4; ++m)
#pragma unroll
                for (int n = 0; n < 4; ++n)
                    acc[m][n] = __builtin_amdgcn_mfma_f32_16x16x32_bf16(a[m], b[n], acc[m][n], 0, 0, 0);
        }
        __syncthreads();
    }

    float* Cf = (float*)Cptr;
    u16* Cb = (u16*)Cptr;
#pragma unroll
    for (int m = 0; m < 4; ++m) {
        int rbase = row0 + wr + m * 16 + lhi * 4;
#pragma unroll
        for (int n = 0; n < 4; ++n) {
            int gcol = col0 + wc + n * 16 + llo;
#pragma unroll
            for (int i = 0; i < 4; ++i) {
                int grow = rbase + i;
                if (grow >= mend) continue;
                long off = (long)grow * ldc + gcol;
                float v = acc[m][n][i];
                if (EPI == 0) {
                    Cf[off] = v;
                } else if (EPI == 1) {
                    float g = bf2f(Gbuf[off]);        // silu(gate) already applied
                    Cb[off] = f2bf(g * v);
                } else if (EPI == 2) {
                    Cb[off] = f2bf(v);
                } else {
                    float s = v / (1.f + expf(-v));   // silu at gate write
                    Cb[off] = f2bf(s);
                }
            }
        }
    }
}

// ---------------- combine: out[t] += w0*eo[r0] + w1*eo[r1] ----------------
__global__ __launch_bounds__(256) void combine_k(float* __restrict__ out,
                                                 const u16* __restrict__ eo,
                                                 const int* __restrict__ invmap,
                                                 const float* __restrict__ wts) {
    int t = blockIdx.x;
    int h = threadIdx.x * 4;
    int r0 = invmap[t * 2], r1 = invmap[t * 2 + 1];
    float w0 = wts[t * 2], w1 = wts[t * 2 + 1];
    float* op = out + (long)t * HDIM + h;
    float4 o = *(float4*)op;
    ushort4 a = *(const ushort4*)(eo + (long)r0 * HDIM + h);
    ushort4 b = *(const ushort4*)(eo + (long)r1 * HDIM + h);
    o.x += w0 * bf2f(a.x) + w1 * bf2f(b.x);
    o.y += w0 * bf2f(a.y) + w1 * bf2f(b.y);
    o.z += w0 * bf2f(a.z) + w1 * bf2f(b.z);
    o.w += w0 * bf2f(a.w) + w1 * bf2f(b.w);
    *(float4*)op = o;
}

extern "C" void kernel_launch(void* const* d_in, const int* in_sizes, int n_in,
                              void* d_out, int out_size, void* d_ws, size_t ws_size,
                              hipStream_t stream) {
    const float* x    = (const float*)d_in[0];
    const float* rw   = (const float*)d_in[1];
    const float* bias = (const float*)d_in[2];
    const float* wg   = (const float*)d_in[3];
    const float* wu   = (const float*)d_in[4];
    const float* wd   = (const float*)d_in[5];
    const float* swg  = (const float*)d_in[6];
    const float* swu  = (const float*)d_in[7];
    const float* swd  = (const float*)d_in[8];
    float* out = (float*)d_out;

    char* ws = (char*)d_ws;
    size_t o = 0;
    auto alloc = [&](size_t bytes) -> void* {
        void* p = ws + o;
        o += (bytes + 255) & ~(size_t)255;
        return p;
    };
    u16* x_bf = (u16*)alloc((size_t)T_TOK * HDIM * 2);
    u16* WtG  = (u16*)alloc((size_t)NEXP * IDIM * HDIM * 2);
    u16* WtU  = (u16*)alloc((size_t)NEXP * IDIM * HDIM * 2);
    u16* WtD  = (u16*)alloc((size_t)NEXP * HDIM * IDIM * 2);
    u16* SWtG = (u16*)alloc((size_t)ISHD * HDIM * 2);
    u16* SWtU = (u16*)alloc((size_t)ISHD * HDIM * 2);
    u16* SWtD = (u16*)alloc((size_t)HDIM * ISHD * 2);
    void* P1  = alloc(16777216);   // shared silu-g bf16 / routed silu-g bf16 / eo bf16 [8192][1024]
    void* P2  = alloc(8388608);    // h1 bf16 [4096][1024] / a_r bf16 [8192][512]
    int*   sel     = (int*)alloc((size_t)T_TOK * 2 * 4);
    float* wts     = (float*)alloc((size_t)T_TOK * 2 * 4);
    int*   invmap  = (int*)alloc((size_t)T_TOK * 2 * 4);
    int*   rowmap  = (int*)alloc((size_t)T_TOK * 2 * 4);
    int*   counts  = (int*)alloc(64);
    int*   offs    = (int*)alloc(128);
    int*   cursors = (int*)alloc(64);

    hipMemsetAsync(counts, 0, 64, stream);

    cvt_f32_bf16<<<dim3((T_TOK * HDIM) / (4 * 256)), 256, 0, stream>>>(x, x_bf, T_TOK * HDIM);

    transpose_k<<<dim3(IDIM / 32, HDIM / 32, NEXP), dim3(32, 8), 0, stream>>>(wg, WtG, HDIM, IDIM, (long)HDIM * IDIM);
    transpose_k<<<dim3(IDIM / 32, HDIM / 32, NEXP), dim3(32, 8), 0, stream>>>(wu, WtU, HDIM, IDIM, (long)HDIM * IDIM);
    transpose_k<<<dim3(HDIM / 32, IDIM / 32, NEXP), dim3(32, 8), 0, stream>>>(wd, WtD, IDIM, HDIM, (long)IDIM * HDIM);
    transpose_k<<<dim3(ISHD / 32, HDIM / 32, 1), dim3(32, 8), 0, stream>>>(swg, SWtG, HDIM, ISHD, (long)HDIM * ISHD);
    transpose_k<<<dim3(ISHD / 32, HDIM / 32, 1), dim3(32, 8), 0, stream>>>(swu, SWtU, HDIM, ISHD, (long)HDIM * ISHD);
    transpose_k<<<dim3(HDIM / 32, ISHD / 32, 1), dim3(32, 8), 0, stream>>>(swd, SWtD, ISHD, HDIM, (long)ISHD * HDIM);

    router_k<<<dim3(T_TOK / 4), 256, 0, stream>>>(x, rw, bias, sel, wts, counts);
    prefix_k<<<dim3(1), 64, 0, stream>>>(counts, offs, cursors);
    build_k<<<dim3(T_TOK / 256), 256, 0, stream>>>(sel, cursors, rowmap, invmap);

    u16* gS = (u16*)P1;
    u16* h1 = (u16*)P2;
    u16* gR = (u16*)P1;
    u16* aR = (u16*)P2;
    u16* eo = (u16*)P1;

    // shared expert: gS = silu(x@swg) bf16 ; h1 = gS*(x@swu) ; out = h1@swd
    gemm_tile<3><<<dim3(ISHD / 128, T_TOK / 128, 1), 256, 0, stream>>>(
        x_bf, HDIM, SWtG, 0, gS, nullptr, ISHD, T_TOK, ISHD, HDIM, nullptr, nullptr);
    gemm_tile<1><<<dim3(ISHD / 128, T_TOK / 128, 1), 256, 0, stream>>>(
        x_bf, HDIM, SWtU, 0, h1, gS, ISHD, T_TOK, ISHD, HDIM, nullptr, nullptr);
    gemm_tile<0><<<dim3(HDIM / 128, T_TOK / 128, 1), 256, 0, stream>>>(
        h1, ISHD, SWtD, 0, out, nullptr, HDIM, T_TOK, HDIM, ISHD, nullptr, nullptr);

    // routed experts: gathered rows per expert
    gemm_tile<3><<<dim3(IDIM / 128, T_TOK / 128, NEXP), 256, 0, stream>>>(
        x_bf, HDIM, WtG, (long)IDIM * HDIM, gR, nullptr, IDIM, T_TOK, IDIM, HDIM, offs, rowmap);
    gemm_tile<1><<<dim3(IDIM / 128, T_TOK / 128, NEXP), 256, 0, stream>>>(
        x_bf, HDIM, WtU, (long)IDIM * HDIM, aR, gR, IDIM, T_TOK, IDIM, HDIM, offs, rowmap);
    gemm_tile<2><<<dim3(HDIM / 128, T_TOK / 128, NEXP), 256, 0, stream>>>(
        aR, IDIM, WtD, (long)HDIM * IDIM, eo, nullptr, HDIM, T_TOK, HDIM, IDIM, offs, nullptr);

    combine_k<<<dim3(T_TOK), 256, 0, stream>>>(out, eo, invmap, wts);
}

// Round 3
// 299.378 us; speedup vs baseline: 1.3831x; 1.3759x over previous
//
#include <hip/hip_runtime.h>
#include <math.h>

#define T_TOK 4096
#define HDIM  1024
#define NEXP  16
#define IDIM  512
#define ISHD  1024

typedef unsigned int u32;
typedef unsigned short u16;
typedef __attribute__((ext_vector_type(8))) short bfrag;   // 8 bf16 (4 VGPRs)
typedef __attribute__((ext_vector_type(4))) float f32x4;

__device__ __forceinline__ u16 f2bf(float f) {
    union { float f; u32 u; } c; c.f = f;
    u32 u = c.u;
    u32 r = u + 0x7fffu + ((u >> 16) & 1u);   // RNE
    return (u16)(r >> 16);
}
__device__ __forceinline__ float bf2f(u16 h) {
    union { u32 u; float f; } c; c.u = ((u32)h) << 16;
    return c.f;
}

__device__ __forceinline__ void async16(void* lds, const void* g) {
    __builtin_amdgcn_global_load_lds((__attribute__((address_space(1))) void*)(g),
                                     (__attribute__((address_space(3))) void*)(lds),
                                     16, 0, 0);
}

// ---------------- f32 -> bf16 convert (x) ----------------
__global__ __launch_bounds__(256) void cvt_f32_bf16(const float* __restrict__ src,
                                                    u16* __restrict__ dst, int n) {
    int i = (blockIdx.x * 256 + threadIdx.x) * 4;
    if (i >= n) return;
    float4 v = *(const float4*)(src + i);
    ushort4 o;
    o.x = f2bf(v.x); o.y = f2bf(v.y); o.z = f2bf(v.z); o.w = f2bf(v.w);
    *(ushort4*)(dst + i) = o;
}

// ---------------- transpose f32 [R][C] -> bf16 [C][R], batched ----------------
__global__ __launch_bounds__(256) void transpose_k(const float* __restrict__ src,
                                                   u16* __restrict__ dst,
                                                   int R, int C, long bstride) {
    __shared__ float tile[32][33];
    long base = (long)blockIdx.z * bstride;
    int c0 = blockIdx.x * 32, r0 = blockIdx.y * 32;
    int tx = threadIdx.x, ty = threadIdx.y;   // (32, 8)
#pragma unroll
    for (int j = 0; j < 4; ++j)
        tile[ty + 8 * j][tx] = src[base + (long)(r0 + ty + 8 * j) * C + (c0 + tx)];
    __syncthreads();
#pragma unroll
    for (int j = 0; j < 4; ++j)
        dst[base + (long)(c0 + ty + 8 * j) * R + (r0 + tx)] = f2bf(tile[tx][ty + 8 * j]);
}

// ---------------- router v3: one wave per token, NO global atomics ----------------
__global__ __launch_bounds__(256) void router_k(const float* __restrict__ x,
                                                const float* __restrict__ rw,
                                                const float* __restrict__ bias,
                                                int* __restrict__ sel,
                                                float* __restrict__ wts) {
    int tid = threadIdx.x;
    int wv = tid >> 6;
    int lane = tid & 63;
    int t = blockIdx.x * 4 + wv;
    int e = lane & 15, hc = lane >> 4;
    const float* xr = x + (long)t * HDIM + hc * 256;
    const float* rp = rw + (long)hc * 256 * NEXP + e;
    float acc = 0.f;
#pragma unroll 4
    for (int i = 0; i < 64; ++i) {
        float4 xv = *(const float4*)(xr + i * 4);
        acc += xv.x * rp[(i * 4 + 0) * NEXP] + xv.y * rp[(i * 4 + 1) * NEXP]
             + xv.z * rp[(i * 4 + 2) * NEXP] + xv.w * rp[(i * 4 + 3) * NEXP];
    }
    acc += __shfl_down(acc, 16);
    acc += __shfl_down(acc, 32);
    float sc = 1.f / (1.f + expf(-acc));       // valid on lanes 0..15
    float v = sc + bias[e];
    int i0 = -1, i1 = -1;
    float v0 = -1e30f, v1 = -1e30f, s0 = 0.f, s1 = 0.f;
#pragma unroll
    for (int j = 0; j < 16; ++j) {
        float vj = __shfl(v, j);
        float scj = __shfl(sc, j);
        if (vj > v0) { v1 = v0; i1 = i0; s1 = s0; v0 = vj; i0 = j; s0 = scj; }
        else if (vj > v1) { v1 = vj; i1 = j; s1 = scj; }
    }
    if (lane == 0) {
        float nrm = s0 + s1 + 1e-20f;
        sel[t * 2] = i0; sel[t * 2 + 1] = i1;
        wts[t * 2] = s0 / nrm; wts[t * 2 + 1] = s1 / nrm;
    }
}

// ---------------- routing build: single block, LDS atomics only ----------------
// histogram -> prefix -> slot assignment. No global atomics (they cost ~13ns
// each serialized on one cacheline = ~100us for 8192 ops).
__global__ __launch_bounds__(1024) void route_build_k(const int* __restrict__ sel,
                                                      int* __restrict__ offs,
                                                      int* __restrict__ rowmap,
                                                      int* __restrict__ invmap) {
    __shared__ int hist[NEXP];
    __shared__ int cur[NEXP];
    int tid = threadIdx.x;
    if (tid < NEXP) hist[tid] = 0;
    __syncthreads();
    for (int i = tid; i < T_TOK * 2; i += 1024)
        atomicAdd(&hist[sel[i]], 1);
    __syncthreads();
    if (tid == 0) {
        int a = 0;
        for (int e2 = 0; e2 < NEXP; ++e2) { cur[e2] = a; offs[e2] = a; a += hist[e2]; }
        offs[NEXP] = a;
    }
    __syncthreads();
    for (int i = tid; i < T_TOK * 2; i += 1024) {
        int e2 = sel[i];
        int slot = atomicAdd(&cur[e2], 1);
        rowmap[slot] = i >> 1;
        invmap[i] = slot;
    }
}

// ---------------- MFMA GEMM: C[M,N] = A[M,K](bf16) @ Bt[N,K]^T(bf16) ----------------
// EPI 0: store f32. EPI 1: read Gbuf(bf16 = silu(g)), store bf16 g*acc.
// EPI 2: store bf16. EPI 3: store bf16 silu(acc).
// offs != null: per-expert row range [offs[e], offs[e+1]) (blockIdx.z = expert).
// rowmap != null: A-row gather through rowmap.
template<int EPI>
__global__ __launch_bounds__(256)
void gemm_tile(const u16* __restrict__ A, int lda,
               const u16* __restrict__ Bt, long strideBt,
               void* __restrict__ Cptr, const u16* __restrict__ Gbuf, int ldc,
               int M, int N, int K,
               const int* __restrict__ offs, const int* __restrict__ rowmap) {
    int e = blockIdx.z;
    int moff = 0, mend = M;
    if (offs) { moff = offs[e]; mend = offs[e + 1]; }
    int row0 = moff + blockIdx.y * 128;
    if (row0 >= mend) return;
    int col0 = blockIdx.x * 128;
    const u16* B = Bt + (long)e * strideBt;

    __shared__ u16 sA[128 * 64];
    __shared__ u16 sB[128 * 64];

    int tid = threadIdx.x;
    int lane = tid & 63;
    int w = tid >> 6;
    int wr = (w >> 1) * 64, wc = (w & 1) * 64;
    int lhi = lane >> 4, llo = lane & 15;

    f32x4 acc[4][4];
#pragma unroll
    for (int m = 0; m < 4; ++m)
#pragma unroll
        for (int n = 0; n < 4; ++n) { f32x4 z = {0.f, 0.f, 0.f, 0.f}; acc[m][n] = z; }

    for (int k0 = 0; k0 < K; k0 += 64) {
#pragma unroll
        for (int c = 0; c < 4; ++c) {
            int idx = c * 256 + tid;          // 0..1023
            int r = idx >> 3, ch = idx & 7;   // row-in-tile, 16B chunk
            int grow = row0 + r;
            int sgrow = (grow < mend) ? grow : moff;
            int arow = rowmap ? rowmap[sgrow] : sgrow;
            async16(&sA[idx * 8], &A[(long)arow * lda + k0 + ch * 8]);
            async16(&sB[idx * 8], &B[(long)(col0 + r) * K + k0 + ch * 8]);
        }
        __syncthreads();
#pragma unroll
        for (int kk = 0; kk < 2; ++kk) {
            bfrag a[4], b[4];
#pragma unroll
            for (int m = 0; m < 4; ++m)
                a[m] = *(const bfrag*)&sA[(wr + m * 16 + llo) * 64 + kk * 32 + lhi * 8];
#pragma unroll
            for (int n = 0; n < 4; ++n)
                b[n] = *(const bfrag*)&sB[(wc + n * 16 + llo) * 64 + kk * 32 + lhi * 8];
#pragma unroll
            for (int m = 0; m < 4; ++m)
#pragma unroll
                for (int n = 0; n < 4; ++n)
                    acc[m][n] = __builtin_amdgcn_mfma_f32_16x16x32_bf16(a[m], b[n], acc[m][n], 0, 0, 0);
        }
        __syncthreads();
    }

    float* Cf = (float*)Cptr;
    u16* Cb = (u16*)Cptr;
#pragma unroll
    for (int m = 0; m < 4; ++m) {
        int rbase = row0 + wr + m * 16 + lhi * 4;
#pragma unroll
        for (int n = 0; n < 4; ++n) {
            int gcol = col0 + wc + n * 16 + llo;
#pragma unroll
            for (int i = 0; i < 4; ++i) {
                int grow = rbase + i;
                if (grow >= mend) continue;
                long off = (long)grow * ldc + gcol;
                float v = acc[m][n][i];
                if (EPI == 0) {
                    Cf[off] = v;
                } else if (EPI == 1) {
                    float g = bf2f(Gbuf[off]);        // silu(gate) already applied
                    Cb[off] = f2bf(g * v);
                } else if (EPI == 2) {
                    Cb[off] = f2bf(v);
                } else {
                    float s = v / (1.f + expf(-v));   // silu at gate write
                    Cb[off] = f2bf(s);
                }
            }
        }
    }
}

// ---------------- combine: out[t] += w0*eo[r0] + w1*eo[r1] ----------------
__global__ __launch_bounds__(256) void combine_k(float* __restrict__ out,
                                                 const u16* __restrict__ eo,
                                                 const int* __restrict__ invmap,
                                                 const float* __restrict__ wts) {
    int t = blockIdx.x;
    int h = threadIdx.x * 4;
    int r0 = invmap[t * 2], r1 = invmap[t * 2 + 1];
    float w0 = wts[t * 2], w1 = wts[t * 2 + 1];
    float* op = out + (long)t * HDIM + h;
    float4 o = *(float4*)op;
    ushort4 a = *(const ushort4*)(eo + (long)r0 * HDIM + h);
    ushort4 b = *(const ushort4*)(eo + (long)r1 * HDIM + h);
    o.x += w0 * bf2f(a.x) + w1 * bf2f(b.x);
    o.y += w0 * bf2f(a.y) + w1 * bf2f(b.y);
    o.z += w0 * bf2f(a.z) + w1 * bf2f(b.z);
    o.w += w0 * bf2f(a.w) + w1 * bf2f(b.w);
    *(float4*)op = o;
}

extern "C" void kernel_launch(void* const* d_in, const int* in_sizes, int n_in,
                              void* d_out, int out_size, void* d_ws, size_t ws_size,
                              hipStream_t stream) {
    const float* x    = (const float*)d_in[0];
    const float* rw   = (const float*)d_in[1];
    const float* bias = (const float*)d_in[2];
    const float* wg   = (const float*)d_in[3];
    const float* wu   = (const float*)d_in[4];
    const float* wd   = (const float*)d_in[5];
    const float* swg  = (const float*)d_in[6];
    const float* swu  = (const float*)d_in[7];
    const float* swd  = (const float*)d_in[8];
    float* out = (float*)d_out;

    char* ws = (char*)d_ws;
    size_t o = 0;
    auto alloc = [&](size_t bytes) -> void* {
        void* p = ws + o;
        o += (bytes + 255) & ~(size_t)255;
        return p;
    };
    u16* x_bf = (u16*)alloc((size_t)T_TOK * HDIM * 2);
    u16* WtG  = (u16*)alloc((size_t)NEXP * IDIM * HDIM * 2);
    u16* WtU  = (u16*)alloc((size_t)NEXP * IDIM * HDIM * 2);
    u16* WtD  = (u16*)alloc((size_t)NEXP * HDIM * IDIM * 2);
    u16* SWtG = (u16*)alloc((size_t)ISHD * HDIM * 2);
    u16* SWtU = (u16*)alloc((size_t)ISHD * HDIM * 2);
    u16* SWtD = (u16*)alloc((size_t)HDIM * ISHD * 2);
    void* P1  = alloc(16777216);   // shared silu-g bf16 / routed silu-g bf16 / eo bf16 [8192][1024]
    void* P2  = alloc(8388608);    // h1 bf16 [4096][1024] / a_r bf16 [8192][512]
    int*   sel     = (int*)alloc((size_t)T_TOK * 2 * 4);
    float* wts     = (float*)alloc((size_t)T_TOK * 2 * 4);
    int*   invmap  = (int*)alloc((size_t)T_TOK * 2 * 4);
    int*   rowmap  = (int*)alloc((size_t)T_TOK * 2 * 4);
    int*   offs    = (int*)alloc(128);

    cvt_f32_bf16<<<dim3((T_TOK * HDIM) / (4 * 256)), 256, 0, stream>>>(x, x_bf, T_TOK * HDIM);

    transpose_k<<<dim3(IDIM / 32, HDIM / 32, NEXP), dim3(32, 8), 0, stream>>>(wg, WtG, HDIM, IDIM, (long)HDIM * IDIM);
    transpose_k<<<dim3(IDIM / 32, HDIM / 32, NEXP), dim3(32, 8), 0, stream>>>(wu, WtU, HDIM, IDIM, (long)HDIM * IDIM);
    transpose_k<<<dim3(HDIM / 32, IDIM / 32, NEXP), dim3(32, 8), 0, stream>>>(wd, WtD, IDIM, HDIM, (long)IDIM * HDIM);
    transpose_k<<<dim3(ISHD / 32, HDIM / 32, 1), dim3(32, 8), 0, stream>>>(swg, SWtG, HDIM, ISHD, (long)HDIM * ISHD);
    transpose_k<<<dim3(ISHD / 32, HDIM / 32, 1), dim3(32, 8), 0, stream>>>(swu, SWtU, HDIM, ISHD, (long)HDIM * ISHD);
    transpose_k<<<dim3(HDIM / 32, ISHD / 32, 1), dim3(32, 8), 0, stream>>>(swd, SWtD, ISHD, HDIM, (long)ISHD * HDIM);

    router_k<<<dim3(T_TOK / 4), 256, 0, stream>>>(x, rw, bias, sel, wts);
    route_build_k<<<dim3(1), 1024, 0, stream>>>(sel, offs, rowmap, invmap);

    u16* gS = (u16*)P1;
    u16* h1 = (u16*)P2;
    u16* gR = (u16*)P1;
    u16* aR = (u16*)P2;
    u16* eo = (u16*)P1;

    // shared expert: gS = silu(x@swg) bf16 ; h1 = gS*(x@swu) ; out = h1@swd
    gemm_tile<3><<<dim3(ISHD / 128, T_TOK / 128, 1), 256, 0, stream>>>(
        x_bf, HDIM, SWtG, 0, gS, nullptr, ISHD, T_TOK, ISHD, HDIM, nullptr, nullptr);
    gemm_tile<1><<<dim3(ISHD / 128, T_TOK / 128, 1), 256, 0, stream>>>(
        x_bf, HDIM, SWtU, 0, h1, gS, ISHD, T_TOK, ISHD, HDIM, nullptr, nullptr);
    gemm_tile<0><<<dim3(HDIM / 128, T_TOK / 128, 1), 256, 0, stream>>>(
        h1, ISHD, SWtD, 0, out, nullptr, HDIM, T_TOK, HDIM, ISHD, nullptr, nullptr);

    // routed experts: gathered rows per expert
    gemm_tile<3><<<dim3(IDIM / 128, T_TOK / 128, NEXP), 256, 0, stream>>>(
        x_bf, HDIM, WtG, (long)IDIM * HDIM, gR, nullptr, IDIM, T_TOK, IDIM, HDIM, offs, rowmap);
    gemm_tile<1><<<dim3(IDIM / 128, T_TOK / 128, NEXP), 256, 0, stream>>>(
        x_bf, HDIM, WtU, (long)IDIM * HDIM, aR, gR, IDIM, T_TOK, IDIM, HDIM, offs, rowmap);
    gemm_tile<2><<<dim3(HDIM / 128, T_TOK / 128, NEXP), 256, 0, stream>>>(
        aR, IDIM, WtD, (long)HDIM * IDIM, eo, nullptr, HDIM, T_TOK, HDIM, IDIM, offs, nullptr);

    combine_k<<<dim3(T_TOK), 256, 0, stream>>>(out, eo, invmap, wts);
}

// Round 4
// 203.164 us; speedup vs baseline: 2.0381x; 1.4736x over previous
//
#include <hip/hip_runtime.h>
#include <math.h>

#define T_TOK 4096
#define HDIM  1024
#define NEXP  16
#define IDIM  512
#define NSLOT 16384          // 8192 routed + 2*4096 shared-pseudo
#define NGRP  18
#define MAXRB 160

typedef unsigned int u32;
typedef unsigned short u16;
typedef __attribute__((ext_vector_type(8))) short bfrag;   // 8 bf16 (4 VGPRs)
typedef __attribute__((ext_vector_type(4))) float f32x4;

__device__ __forceinline__ u16 f2bf(float f) {
    union { float f; u32 u; } c; c.f = f;
    u32 u = c.u;
    u32 r = u + 0x7fffu + ((u >> 16) & 1u);   // RNE
    return (u16)(r >> 16);
}
__device__ __forceinline__ float bf2f(u16 h) {
    union { u32 u; float f; } c; c.u = ((u32)h) << 16;
    return c.f;
}

__device__ __forceinline__ void async16(void* lds, const void* g) {
    __builtin_amdgcn_global_load_lds((__attribute__((address_space(1))) void*)(g),
                                     (__attribute__((address_space(3))) void*)(lds),
                                     16, 0, 0);
}

// ---------------- f32 -> bf16 convert (x) ----------------
__global__ __launch_bounds__(256) void cvt_f32_bf16(const float* __restrict__ src,
                                                    u16* __restrict__ dst, int n) {
    int i = (blockIdx.x * 256 + threadIdx.x) * 4;
    if (i >= n) return;
    float4 v = *(const float4*)(src + i);
    ushort4 o;
    o.x = f2bf(v.x); o.y = f2bf(v.y); o.z = f2bf(v.z); o.w = f2bf(v.w);
    *(ushort4*)(dst + i) = o;
}

// ---------------- transpose f32 [R][C] -> bf16 [C][R], batched ----------------
__global__ __launch_bounds__(256) void transpose_k(const float* __restrict__ src,
                                                   u16* __restrict__ dst,
                                                   int R, int C, long bstride) {
    __shared__ float tile[32][33];
    long base = (long)blockIdx.z * bstride;
    int c0 = blockIdx.x * 32, r0 = blockIdx.y * 32;
    int tx = threadIdx.x, ty = threadIdx.y;   // (32, 8)
#pragma unroll
    for (int j = 0; j < 4; ++j)
        tile[ty + 8 * j][tx] = src[base + (long)(r0 + ty + 8 * j) * C + (c0 + tx)];
    __syncthreads();
#pragma unroll
    for (int j = 0; j < 4; ++j)
        dst[base + (long)(c0 + ty + 8 * j) * R + (r0 + tx)] = f2bf(tile[tx][ty + 8 * j]);
}

// ---------------- router: one wave per token, no global atomics ----------------
__global__ __launch_bounds__(256) void router_k(const float* __restrict__ x,
                                                const float* __restrict__ rw,
                                                const float* __restrict__ bias,
                                                int* __restrict__ sel,
                                                float* __restrict__ wts) {
    int tid = threadIdx.x;
    int wv = tid >> 6;
    int lane = tid & 63;
    int t = blockIdx.x * 4 + wv;
    int e = lane & 15, hc = lane >> 4;
    const float* xr = x + (long)t * HDIM + hc * 256;
    const float* rp = rw + (long)hc * 256 * NEXP + e;
    float acc = 0.f;
#pragma unroll 4
    for (int i = 0; i < 64; ++i) {
        float4 xv = *(const float4*)(xr + i * 4);
        acc += xv.x * rp[(i * 4 + 0) * NEXP] + xv.y * rp[(i * 4 + 1) * NEXP]
             + xv.z * rp[(i * 4 + 2) * NEXP] + xv.w * rp[(i * 4 + 3) * NEXP];
    }
    acc += __shfl_down(acc, 16);
    acc += __shfl_down(acc, 32);
    float sc = 1.f / (1.f + expf(-acc));       // valid on lanes 0..15
    float v = sc + bias[e];
    int i0 = -1, i1 = -1;
    float v0 = -1e30f, v1 = -1e30f, s0 = 0.f, s1 = 0.f;
#pragma unroll
    for (int j = 0; j < 16; ++j) {
        float vj = __shfl(v, j);
        float scj = __shfl(sc, j);
        if (vj > v0) { v1 = v0; i1 = i0; s1 = s0; v0 = vj; i0 = j; s0 = scj; }
        else if (vj > v1) { v1 = vj; i1 = j; s1 = scj; }
    }
    if (lane == 0) {
        float nrm = s0 + s1 + 1e-20f;
        sel[t * 2] = i0; sel[t * 2 + 1] = i1;
        wts[t * 2] = s0 / nrm; wts[t * 2 + 1] = s1 / nrm;
    }
}

// ---------------- routing build: single block, LDS atomics only ----------------
// histogram -> prefix -> slot assignment -> row-block tables for grouped GEMM.
// Groups 0..15 = routed experts; 16,17 = shared pseudo-experts (all tokens).
__global__ __launch_bounds__(1024) void route_build_k(const int* __restrict__ sel,
                                                      int* __restrict__ offs,
                                                      int* __restrict__ rowmap,
                                                      int* __restrict__ invmap,
                                                      int* __restrict__ rbGroup,
                                                      int* __restrict__ rbRow0) {
    __shared__ int hist[NEXP];
    __shared__ int cur[NEXP];
    int tid = threadIdx.x;
    if (tid < NEXP) hist[tid] = 0;
    __syncthreads();
    for (int i = tid; i < T_TOK * 2; i += 1024)
        atomicAdd(&hist[sel[i]], 1);
    __syncthreads();
    if (tid == 0) {
        int a = 0;
        for (int g = 0; g < NEXP; ++g) { cur[g] = a; offs[g] = a; a += hist[g]; }
        offs[16] = 8192;
        offs[17] = 8192 + T_TOK;
        offs[18] = 8192 + 2 * T_TOK;
        int rb = 0;
        for (int g = 0; g < NGRP; ++g)
            for (int r0 = offs[g]; r0 < offs[g + 1]; r0 += 128) {
                rbGroup[rb] = g; rbRow0[rb] = r0; ++rb;
            }
        for (; rb < MAXRB; ++rb) rbGroup[rb] = -1;
    }
    __syncthreads();
    for (int i = tid; i < T_TOK * 2; i += 1024) {
        int g = sel[i];
        int slot = atomicAdd(&cur[g], 1);
        rowmap[slot] = i >> 1;
        invmap[i] = slot;
    }
    for (int i = tid; i < T_TOK; i += 1024) {
        rowmap[8192 + i] = i;
        rowmap[8192 + T_TOK + i] = i;
    }
}

// ---------------- grouped fused gate+up GEMM ----------------
// 128-row x 64-col tile over slot space; K = HDIM. Writes H[slot][I]=silu(g)*u bf16.
__global__ __launch_bounds__(256)
void gemm_gu(const u16* __restrict__ A,            // x_bf [T][H]
             const u16* __restrict__ WG,           // [16][512][1024]
             const u16* __restrict__ WU,
             const u16* __restrict__ SWG,          // [2*512][1024]
             const u16* __restrict__ SWU,
             u16* __restrict__ H,                  // [NSLOT][512]
             const int* __restrict__ offs,
             const int* __restrict__ rowmap,
             const int* __restrict__ rbGroup,
             const int* __restrict__ rbRow0) {
    int rb = blockIdx.y;
    int g = rbGroup[rb];
    if (g < 0) return;
    int row0 = rbRow0[rb];
    int mend = offs[g + 1];
    int col0 = blockIdx.x * 64;
    long wb = (long)((g < 16) ? g : (g - 16)) * IDIM * HDIM;
    const u16* Bg = (g < 16) ? WG + wb : SWG + wb;
    const u16* Bu = (g < 16) ? WU + wb : SWU + wb;

    __shared__ u16 sA[128 * 64];
    __shared__ u16 sBg[64 * 64];
    __shared__ u16 sBu[64 * 64];

    int tid = threadIdx.x;
    int lane = tid & 63;
    int w = tid >> 6;
    int wr = (w >> 1) * 64, wc = (w & 1) * 32;
    int lhi = lane >> 4, llo = lane & 15;

    int arow[4];
#pragma unroll
    for (int c = 0; c < 4; ++c) {
        int r = (c * 256 + tid) >> 3;
        int grow = row0 + r;
        arow[c] = rowmap[(grow < mend) ? grow : row0];
    }

    f32x4 accg[4][2], accu[4][2];
#pragma unroll
    for (int m = 0; m < 4; ++m)
#pragma unroll
        for (int n = 0; n < 2; ++n) {
            f32x4 z = {0.f, 0.f, 0.f, 0.f};
            accg[m][n] = z; accu[m][n] = z;
        }

    for (int k0 = 0; k0 < HDIM; k0 += 64) {
#pragma unroll
        for (int c = 0; c < 4; ++c) {
            int idx = c * 256 + tid;
            int ch = idx & 7;
            async16(&sA[idx * 8], &A[(long)arow[c] * HDIM + k0 + ch * 8]);
        }
#pragma unroll
        for (int c = 0; c < 2; ++c) {
            int idx = c * 256 + tid;
            int r = idx >> 3, ch = idx & 7;
            async16(&sBg[idx * 8], &Bg[(long)(col0 + r) * HDIM + k0 + ch * 8]);
            async16(&sBu[idx * 8], &Bu[(long)(col0 + r) * HDIM + k0 + ch * 8]);
        }
        __syncthreads();
#pragma unroll
        for (int kk = 0; kk < 2; ++kk) {
            bfrag a[4], bg[2], bu[2];
#pragma unroll
            for (int m = 0; m < 4; ++m)
                a[m] = *(const bfrag*)&sA[(wr + m * 16 + llo) * 64 + kk * 32 + lhi * 8];
#pragma unroll
            for (int n = 0; n < 2; ++n) {
                bg[n] = *(const bfrag*)&sBg[(wc + n * 16 + llo) * 64 + kk * 32 + lhi * 8];
                bu[n] = *(const bfrag*)&sBu[(wc + n * 16 + llo) * 64 + kk * 32 + lhi * 8];
            }
#pragma unroll
            for (int m = 0; m < 4; ++m)
#pragma unroll
                for (int n = 0; n < 2; ++n) {
                    accg[m][n] = __builtin_amdgcn_mfma_f32_16x16x32_bf16(a[m], bg[n], accg[m][n], 0, 0, 0);
                    accu[m][n] = __builtin_amdgcn_mfma_f32_16x16x32_bf16(a[m], bu[n], accu[m][n], 0, 0, 0);
                }
        }
        __syncthreads();
    }

#pragma unroll
    for (int m = 0; m < 4; ++m) {
        int rbase = row0 + wr + m * 16 + lhi * 4;
#pragma unroll
        for (int n = 0; n < 2; ++n) {
            int col = col0 + wc + n * 16 + llo;
#pragma unroll
            for (int i = 0; i < 4; ++i) {
                int grow = rbase + i;
                if (grow >= mend) continue;
                float gv = accg[m][n][i], uv = accu[m][n][i];
                float hv = gv / (1.f + expf(-gv)) * uv;
                H[(long)grow * IDIM + col] = f2bf(hv);
            }
        }
    }
}

// ---------------- grouped down GEMM: EO[slot][H] = H[slot][I] @ Wd ----------------
__global__ __launch_bounds__(256)
void gemm_down(const u16* __restrict__ Hbuf,       // [NSLOT][512]
               const u16* __restrict__ WD,         // [16][1024][512]
               const u16* __restrict__ SWD,        // [2][1024][512]
               u16* __restrict__ EO,               // [NSLOT][1024]
               const int* __restrict__ offs,
               const int* __restrict__ rbGroup,
               const int* __restrict__ rbRow0) {
    int rb = blockIdx.y;
    int g = rbGroup[rb];
    if (g < 0) return;
    int row0 = rbRow0[rb];
    int mend = offs[g + 1];
    int col0 = blockIdx.x * 128;
    long wb = (long)((g < 16) ? g : (g - 16)) * HDIM * IDIM;
    const u16* B = (g < 16) ? WD + wb : SWD + wb;

    __shared__ u16 sA[128 * 64];
    __shared__ u16 sB[128 * 64];

    int tid = threadIdx.x;
    int lane = tid & 63;
    int w = tid >> 6;
    int wr = (w >> 1) * 64, wc = (w & 1) * 64;
    int lhi = lane >> 4, llo = lane & 15;

    int arow[4];
#pragma unroll
    for (int c = 0; c < 4; ++c) {
        int r = (c * 256 + tid) >> 3;
        int grow = row0 + r;
        arow[c] = (grow < mend) ? grow : row0;
    }

    f32x4 acc[4][4];
#pragma unroll
    for (int m = 0; m < 4; ++m)
#pragma unroll
        for (int n = 0; n < 4; ++n) { f32x4 z = {0.f, 0.f, 0.f, 0.f}; acc[m][n] = z; }

    for (int k0 = 0; k0 < IDIM; k0 += 64) {
#pragma unroll
        for (int c = 0; c < 4; ++c) {
            int idx = c * 256 + tid;
            int r = idx >> 3, ch = idx & 7;
            async16(&sA[idx * 8], &Hbuf[(long)arow[c] * IDIM + k0 + ch * 8]);
            async16(&sB[idx * 8], &B[(long)(col0 + r) * IDIM + k0 + ch * 8]);
        }
        __syncthreads();
#pragma unroll
        for (int kk = 0; kk < 2; ++kk) {
            bfrag a[4], b[4];
#pragma unroll
            for (int m = 0; m < 4; ++m)
                a[m] = *(const bfrag*)&sA[(wr + m * 16 + llo) * 64 + kk * 32 + lhi * 8];
#pragma unroll
            for (int n = 0; n < 4; ++n)
                b[n] = *(const bfrag*)&sB[(wc + n * 16 + llo) * 64 + kk * 32 + lhi * 8];
#pragma unroll
            for (int m = 0; m < 4; ++m)
#pragma unroll
                for (int n = 0; n < 4; ++n)
                    acc[m][n] = __builtin_amdgcn_mfma_f32_16x16x32_bf16(a[m], b[n], acc[m][n], 0, 0, 0);
        }
        __syncthreads();
    }

#pragma unroll
    for (int m = 0; m < 4; ++m) {
        int rbase = row0 + wr + m * 16 + lhi * 4;
#pragma unroll
        for (int n = 0; n < 4; ++n) {
            int col = col0 + wc + n * 16 + llo;
#pragma unroll
            for (int i = 0; i < 4; ++i) {
                int grow = rbase + i;
                if (grow >= mend) continue;
                EO[(long)grow * HDIM + col] = f2bf(acc[m][n][i]);
            }
        }
    }
}

// ---------------- combine: out = w0*eo[r0] + w1*eo[r1] + eo[sh0] + eo[sh1] ----------------
__global__ __launch_bounds__(256) void combine_k(float* __restrict__ out,
                                                 const u16* __restrict__ eo,
                                                 const int* __restrict__ invmap,
                                                 const float* __restrict__ wts) {
    int t = blockIdx.x;
    int h = threadIdx.x * 4;
    int r0 = invmap[t * 2], r1 = invmap[t * 2 + 1];
    float w0 = wts[t * 2], w1 = wts[t * 2 + 1];
    int s0 = 8192 + t, s1 = 8192 + T_TOK + t;
    ushort4 a = *(const ushort4*)(eo + (long)r0 * HDIM + h);
    ushort4 b = *(const ushort4*)(eo + (long)r1 * HDIM + h);
    ushort4 c = *(const ushort4*)(eo + (long)s0 * HDIM + h);
    ushort4 d = *(const ushort4*)(eo + (long)s1 * HDIM + h);
    float4 o;
    o.x = w0 * bf2f(a.x) + w1 * bf2f(b.x) + bf2f(c.x) + bf2f(d.x);
    o.y = w0 * bf2f(a.y) + w1 * bf2f(b.y) + bf2f(c.y) + bf2f(d.y);
    o.z = w0 * bf2f(a.z) + w1 * bf2f(b.z) + bf2f(c.z) + bf2f(d.z);
    o.w = w0 * bf2f(a.w) + w1 * bf2f(b.w) + bf2f(c.w) + bf2f(d.w);
    *(float4*)(out + (long)t * HDIM + h) = o;
}

extern "C" void kernel_launch(void* const* d_in, const int* in_sizes, int n_in,
                              void* d_out, int out_size, void* d_ws, size_t ws_size,
                              hipStream_t stream) {
    const float* x    = (const float*)d_in[0];
    const float* rw   = (const float*)d_in[1];
    const float* bias = (const float*)d_in[2];
    const float* wg   = (const float*)d_in[3];
    const float* wu   = (const float*)d_in[4];
    const float* wd   = (const float*)d_in[5];
    const float* swg  = (const float*)d_in[6];
    const float* swu  = (const float*)d_in[7];
    const float* swd  = (const float*)d_in[8];
    float* out = (float*)d_out;

    char* ws = (char*)d_ws;
    size_t o = 0;
    auto alloc = [&](size_t bytes) -> void* {
        void* p = ws + o;
        o += (bytes + 255) & ~(size_t)255;
        return p;
    };
    u16* x_bf = (u16*)alloc((size_t)T_TOK * HDIM * 2);
    u16* WtG  = (u16*)alloc((size_t)NEXP * IDIM * HDIM * 2);   // 16 MB
    u16* WtU  = (u16*)alloc((size_t)NEXP * IDIM * HDIM * 2);   // 16 MB (contiguous after WtG)
    u16* WtD  = (u16*)alloc((size_t)NEXP * HDIM * IDIM * 2);
    u16* SWtG = (u16*)alloc((size_t)2 * IDIM * HDIM * 2);
    u16* SWtU = (u16*)alloc((size_t)2 * IDIM * HDIM * 2);
    u16* SWtD = (u16*)alloc((size_t)2 * HDIM * IDIM * 2);
    u16* Hbuf = (u16*)alloc((size_t)NSLOT * IDIM * 2);         // 16 MB
    int*   sel     = (int*)alloc((size_t)T_TOK * 2 * 4);
    float* wts     = (float*)alloc((size_t)T_TOK * 2 * 4);
    int*   invmap  = (int*)alloc((size_t)T_TOK * 2 * 4);
    int*   rowmap  = (int*)alloc((size_t)NSLOT * 4);
    int*   offs    = (int*)alloc((NGRP + 1) * 4);
    int*   rbGroup = (int*)alloc(MAXRB * 4);
    int*   rbRow0  = (int*)alloc(MAXRB * 4);
    // EO (32 MB) aliases WtG+WtU, which are dead after gemm_gu completes.
    u16* EO = WtG;

    cvt_f32_bf16<<<dim3((T_TOK * HDIM) / (4 * 256)), 256, 0, stream>>>(x, x_bf, T_TOK * HDIM);

    // routed weights -> bf16, [N][K] layouts
    transpose_k<<<dim3(IDIM / 32, HDIM / 32, NEXP), dim3(32, 8), 0, stream>>>(wg, WtG, HDIM, IDIM, (long)HDIM * IDIM);
    transpose_k<<<dim3(IDIM / 32, HDIM / 32, NEXP), dim3(32, 8), 0, stream>>>(wu, WtU, HDIM, IDIM, (long)HDIM * IDIM);
    transpose_k<<<dim3(HDIM / 32, IDIM / 32, NEXP), dim3(32, 8), 0, stream>>>(wd, WtD, IDIM, HDIM, (long)IDIM * HDIM);
    // shared weights as 2 pseudo-experts
    transpose_k<<<dim3(32, 32, 1), dim3(32, 8), 0, stream>>>(swg, SWtG, HDIM, 2 * IDIM, 0);
    transpose_k<<<dim3(32, 32, 1), dim3(32, 8), 0, stream>>>(swu, SWtU, HDIM, 2 * IDIM, 0);
    transpose_k<<<dim3(HDIM / 32, IDIM / 32, 2), dim3(32, 8), 0, stream>>>(swd, SWtD, IDIM, HDIM, (long)IDIM * HDIM);

    router_k<<<dim3(T_TOK / 4), 256, 0, stream>>>(x, rw, bias, sel, wts);
    route_build_k<<<dim3(1), 1024, 0, stream>>>(sel, offs, rowmap, invmap, rbGroup, rbRow0);

    gemm_gu<<<dim3(IDIM / 64, MAXRB), 256, 0, stream>>>(
        x_bf, WtG, WtU, SWtG, SWtU, Hbuf, offs, rowmap, rbGroup, rbRow0);

    gemm_down<<<dim3(HDIM / 128, MAXRB), 256, 0, stream>>>(
        Hbuf, WtD, SWtD, EO, offs, rbGroup, rbRow0);

    combine_k<<<dim3(T_TOK), 256, 0, stream>>>(out, EO, invmap, wts);
}

// Round 5
// 175.998 us; speedup vs baseline: 2.3527x; 1.1544x over previous
//
#include <hip/hip_runtime.h>
#include <math.h>

#define T_TOK 4096
#define HDIM  1024
#define NEXP  16
#define IDIM  512
#define NSLOT 16384          // 8192 routed + 2*4096 shared-pseudo
#define NGRP  18
#define MAXRB 160

typedef unsigned int u32;
typedef unsigned short u16;
typedef __attribute__((ext_vector_type(8))) short bfrag;   // 8 bf16 (4 VGPRs)
typedef __attribute__((ext_vector_type(4))) float f32x4;

__device__ __forceinline__ u16 f2bf(float f) {
    union { float f; u32 u; } c; c.f = f;
    u32 u = c.u;
    u32 r = u + 0x7fffu + ((u >> 16) & 1u);   // RNE
    return (u16)(r >> 16);
}
__device__ __forceinline__ float bf2f(u16 h) {
    union { u32 u; float f; } c; c.u = ((u32)h) << 16;
    return c.f;
}

__device__ __forceinline__ void async16(void* lds, const void* g) {
    __builtin_amdgcn_global_load_lds((__attribute__((address_space(1))) void*)(g),
                                     (__attribute__((address_space(3))) void*)(lds),
                                     16, 0, 0);
}

// ---------------- f32 -> bf16 convert (x) ----------------
__global__ __launch_bounds__(256) void cvt_f32_bf16(const float* __restrict__ src,
                                                    u16* __restrict__ dst, int n) {
    int i = (blockIdx.x * 256 + threadIdx.x) * 4;
    if (i >= n) return;
    float4 v = *(const float4*)(src + i);
    ushort4 o;
    o.x = f2bf(v.x); o.y = f2bf(v.y); o.z = f2bf(v.z); o.w = f2bf(v.w);
    *(ushort4*)(dst + i) = o;
}

// ---------------- transpose f32 [R][C] -> bf16 [C][R], batched ----------------
__global__ __launch_bounds__(256) void transpose_k(const float* __restrict__ src,
                                                   u16* __restrict__ dst,
                                                   int R, int C, long bstride) {
    __shared__ float tile[32][33];
    long base = (long)blockIdx.z * bstride;
    int c0 = blockIdx.x * 32, r0 = blockIdx.y * 32;
    int tx = threadIdx.x, ty = threadIdx.y;   // (32, 8)
#pragma unroll
    for (int j = 0; j < 4; ++j)
        tile[ty + 8 * j][tx] = src[base + (long)(r0 + ty + 8 * j) * C + (c0 + tx)];
    __syncthreads();
#pragma unroll
    for (int j = 0; j < 4; ++j)
        dst[base + (long)(c0 + ty + 8 * j) * R + (r0 + tx)] = f2bf(tile[tx][ty + 8 * j]);
}

// ---------------- router: one wave per token, no global atomics ----------------
__global__ __launch_bounds__(256) void router_k(const float* __restrict__ x,
                                                const float* __restrict__ rw,
                                                const float* __restrict__ bias,
                                                int* __restrict__ sel,
                                                float* __restrict__ wts) {
    int tid = threadIdx.x;
    int wv = tid >> 6;
    int lane = tid & 63;
    int t = blockIdx.x * 4 + wv;
    int e = lane & 15, hc = lane >> 4;
    const float* xr = x + (long)t * HDIM + hc * 256;
    const float* rp = rw + (long)hc * 256 * NEXP + e;
    float acc = 0.f;
#pragma unroll 4
    for (int i = 0; i < 64; ++i) {
        float4 xv = *(const float4*)(xr + i * 4);
        acc += xv.x * rp[(i * 4 + 0) * NEXP] + xv.y * rp[(i * 4 + 1) * NEXP]
             + xv.z * rp[(i * 4 + 2) * NEXP] + xv.w * rp[(i * 4 + 3) * NEXP];
    }
    acc += __shfl_down(acc, 16);
    acc += __shfl_down(acc, 32);
    float sc = 1.f / (1.f + __expf(-acc));     // valid on lanes 0..15
    float v = sc + bias[e];
    int i0 = -1, i1 = -1;
    float v0 = -1e30f, v1 = -1e30f, s0 = 0.f, s1 = 0.f;
#pragma unroll
    for (int j = 0; j < 16; ++j) {
        float vj = __shfl(v, j);
        float scj = __shfl(sc, j);
        if (vj > v0) { v1 = v0; i1 = i0; s1 = s0; v0 = vj; i0 = j; s0 = scj; }
        else if (vj > v1) { v1 = vj; i1 = j; s1 = scj; }
    }
    if (lane == 0) {
        float nrm = s0 + s1 + 1e-20f;
        sel[t * 2] = i0; sel[t * 2 + 1] = i1;
        wts[t * 2] = s0 / nrm; wts[t * 2 + 1] = s1 / nrm;
    }
}

// ---------------- routing build: single block, LDS atomics only ----------------
__global__ __launch_bounds__(1024) void route_build_k(const int* __restrict__ sel,
                                                      int* __restrict__ offs,
                                                      int* __restrict__ rowmap,
                                                      int* __restrict__ invmap,
                                                      int* __restrict__ rbGroup,
                                                      int* __restrict__ rbRow0) {
    __shared__ int hist[NEXP];
    __shared__ int cur[NEXP];
    int tid = threadIdx.x;
    if (tid < NEXP) hist[tid] = 0;
    __syncthreads();
    for (int i = tid; i < T_TOK * 2; i += 1024)
        atomicAdd(&hist[sel[i]], 1);
    __syncthreads();
    if (tid == 0) {
        int a = 0;
        for (int g = 0; g < NEXP; ++g) { cur[g] = a; offs[g] = a; a += hist[g]; }
        offs[16] = 8192;
        offs[17] = 8192 + T_TOK;
        offs[18] = 8192 + 2 * T_TOK;
        int rb = 0;
        for (int g = 0; g < NGRP; ++g)
            for (int r0 = offs[g]; r0 < offs[g + 1]; r0 += 128) {
                rbGroup[rb] = g; rbRow0[rb] = r0; ++rb;
            }
        for (; rb < MAXRB; ++rb) rbGroup[rb] = -1;
    }
    __syncthreads();
    for (int i = tid; i < T_TOK * 2; i += 1024) {
        int g = sel[i];
        int slot = atomicAdd(&cur[g], 1);
        rowmap[slot] = i >> 1;
        invmap[i] = slot;
    }
    for (int i = tid; i < T_TOK; i += 1024) {
        rowmap[8192 + i] = i;
        rowmap[8192 + T_TOK + i] = i;
    }
}

// ---------------- grouped fused gate+up GEMM ----------------
// 128-row x 64-col tile over slot space; K = HDIM. Writes H[slot][I]=silu(g)*u bf16.
// LDS: linear dest (global_load_lds), source chunk index XOR (r&7), fragment
// reads XOR the same involution -> 2-way bank aliasing (free).
__global__ __launch_bounds__(256)
void gemm_gu(const u16* __restrict__ A,            // x_bf [T][H]
             const u16* __restrict__ WG,           // [16][512][1024]
             const u16* __restrict__ WU,
             const u16* __restrict__ SWG,          // [2*512][1024]
             const u16* __restrict__ SWU,
             u16* __restrict__ H,                  // [NSLOT][512]
             const int* __restrict__ offs,
             const int* __restrict__ rowmap,
             const int* __restrict__ rbGroup,
             const int* __restrict__ rbRow0) {
    int rb = blockIdx.y;
    int g = rbGroup[rb];
    if (g < 0) return;
    int row0 = rbRow0[rb];
    int mend = offs[g + 1];
    int col0 = blockIdx.x * 64;
    long wb = (long)((g < 16) ? g : (g - 16)) * IDIM * HDIM;
    const u16* Bg = (g < 16) ? WG + wb : SWG + wb;
    const u16* Bu = (g < 16) ? WU + wb : SWU + wb;

    __shared__ u16 sA[128 * 64];
    __shared__ u16 sBg[64 * 64];
    __shared__ u16 sBu[64 * 64];

    int tid = threadIdx.x;
    int lane = tid & 63;
    int w = tid >> 6;
    int wr = (w >> 1) * 64, wc = (w & 1) * 32;
    int lhi = lane >> 4, llo = lane & 15;
    int swz = llo & 7;

    // hoisted staging pointers (swizzled global source, linear LDS dest)
    const u16* pA[4]; u16* dA[4];
#pragma unroll
    for (int c = 0; c < 4; ++c) {
        int idx = c * 256 + tid;
        int r = idx >> 3, ch = idx & 7;
        int grow = row0 + r;
        int ar = rowmap[(grow < mend) ? grow : row0];
        pA[c] = A + (long)ar * HDIM + ((ch ^ (r & 7)) * 8);
        dA[c] = &sA[idx * 8];
    }
    const u16* pBg[2]; const u16* pBu[2]; u16* dBg[2]; u16* dBu[2];
#pragma unroll
    for (int c = 0; c < 2; ++c) {
        int idx = c * 256 + tid;
        int r = idx >> 3, ch = idx & 7;
        long boff = (long)(col0 + r) * HDIM + ((ch ^ (r & 7)) * 8);
        pBg[c] = Bg + boff; pBu[c] = Bu + boff;
        dBg[c] = &sBg[idx * 8]; dBu[c] = &sBu[idx * 8];
    }

    f32x4 accg[4][2], accu[4][2];
#pragma unroll
    for (int m = 0; m < 4; ++m)
#pragma unroll
        for (int n = 0; n < 2; ++n) {
            f32x4 z = {0.f, 0.f, 0.f, 0.f};
            accg[m][n] = z; accu[m][n] = z;
        }

    for (int k0 = 0; k0 < HDIM; k0 += 64) {
#pragma unroll
        for (int c = 0; c < 4; ++c) { async16(dA[c], pA[c]); pA[c] += 64; }
#pragma unroll
        for (int c = 0; c < 2; ++c) {
            async16(dBg[c], pBg[c]); pBg[c] += 64;
            async16(dBu[c], pBu[c]); pBu[c] += 64;
        }
        __syncthreads();
#pragma unroll
        for (int kk = 0; kk < 2; ++kk) {
            int p = ((kk * 4 + lhi) ^ swz) * 8;   // swizzled chunk position
            bfrag a[4], bg[2], bu[2];
#pragma unroll
            for (int m = 0; m < 4; ++m)
                a[m] = *(const bfrag*)&sA[(wr + m * 16 + llo) * 64 + p];
#pragma unroll
            for (int n = 0; n < 2; ++n) {
                bg[n] = *(const bfrag*)&sBg[(wc + n * 16 + llo) * 64 + p];
                bu[n] = *(const bfrag*)&sBu[(wc + n * 16 + llo) * 64 + p];
            }
#pragma unroll
            for (int m = 0; m < 4; ++m)
#pragma unroll
                for (int n = 0; n < 2; ++n) {
                    accg[m][n] = __builtin_amdgcn_mfma_f32_16x16x32_bf16(a[m], bg[n], accg[m][n], 0, 0, 0);
                    accu[m][n] = __builtin_amdgcn_mfma_f32_16x16x32_bf16(a[m], bu[n], accu[m][n], 0, 0, 0);
                }
        }
        __syncthreads();
    }

#pragma unroll
    for (int m = 0; m < 4; ++m) {
        int rbase = row0 + wr + m * 16 + lhi * 4;
#pragma unroll
        for (int n = 0; n < 2; ++n) {
            int col = col0 + wc + n * 16 + llo;
#pragma unroll
            for (int i = 0; i < 4; ++i) {
                int grow = rbase + i;
                if (grow >= mend) continue;
                float gv = accg[m][n][i], uv = accu[m][n][i];
                float hv = gv / (1.f + __expf(-gv)) * uv;
                H[(long)grow * IDIM + col] = f2bf(hv);
            }
        }
    }
}

// ---------------- grouped down GEMM: EO[slot][H] = H[slot][I] @ Wd ----------------
__global__ __launch_bounds__(256)
void gemm_down(const u16* __restrict__ Hbuf,       // [NSLOT][512]
               const u16* __restrict__ WD,         // [16][1024][512]
               const u16* __restrict__ SWD,        // [2][1024][512]
               u16* __restrict__ EO,               // [NSLOT][1024]
               const int* __restrict__ offs,
               const int* __restrict__ rbGroup,
               const int* __restrict__ rbRow0) {
    int rb = blockIdx.y;
    int g = rbGroup[rb];
    if (g < 0) return;
    int row0 = rbRow0[rb];
    int mend = offs[g + 1];
    int col0 = blockIdx.x * 128;
    long wb = (long)((g < 16) ? g : (g - 16)) * HDIM * IDIM;
    const u16* B = (g < 16) ? WD + wb : SWD + wb;

    __shared__ u16 sA[128 * 64];
    __shared__ u16 sB[128 * 64];

    int tid = threadIdx.x;
    int lane = tid & 63;
    int w = tid >> 6;
    int wr = (w >> 1) * 64, wc = (w & 1) * 64;
    int lhi = lane >> 4, llo = lane & 15;
    int swz = llo & 7;

    const u16* pA[4]; const u16* pB[4]; u16* dA[4]; u16* dB[4];
#pragma unroll
    for (int c = 0; c < 4; ++c) {
        int idx = c * 256 + tid;
        int r = idx >> 3, ch = idx & 7;
        int grow = row0 + r;
        int ar = (grow < mend) ? grow : row0;
        int chs = (ch ^ (r & 7)) * 8;
        pA[c] = Hbuf + (long)ar * IDIM + chs;
        pB[c] = B + (long)(col0 + r) * IDIM + chs;
        dA[c] = &sA[idx * 8];
        dB[c] = &sB[idx * 8];
    }

    f32x4 acc[4][4];
#pragma unroll
    for (int m = 0; m < 4; ++m)
#pragma unroll
        for (int n = 0; n < 4; ++n) { f32x4 z = {0.f, 0.f, 0.f, 0.f}; acc[m][n] = z; }

    for (int k0 = 0; k0 < IDIM; k0 += 64) {
#pragma unroll
        for (int c = 0; c < 4; ++c) {
            async16(dA[c], pA[c]); pA[c] += 64;
            async16(dB[c], pB[c]); pB[c] += 64;
        }
        __syncthreads();
#pragma unroll
        for (int kk = 0; kk < 2; ++kk) {
            int p = ((kk * 4 + lhi) ^ swz) * 8;
            bfrag a[4], b[4];
#pragma unroll
            for (int m = 0; m < 4; ++m)
                a[m] = *(const bfrag*)&sA[(wr + m * 16 + llo) * 64 + p];
#pragma unroll
            for (int n = 0; n < 4; ++n)
                b[n] = *(const bfrag*)&sB[(wc + n * 16 + llo) * 64 + p];
#pragma unroll
            for (int m = 0; m < 4; ++m)
#pragma unroll
                for (int n = 0; n < 4; ++n)
                    acc[m][n] = __builtin_amdgcn_mfma_f32_16x16x32_bf16(a[m], b[n], acc[m][n], 0, 0, 0);
        }
        __syncthreads();
    }

#pragma unroll
    for (int m = 0; m < 4; ++m) {
        int rbase = row0 + wr + m * 16 + lhi * 4;
#pragma unroll
        for (int n = 0; n < 4; ++n) {
            int col = col0 + wc + n * 16 + llo;
#pragma unroll
            for (int i = 0; i < 4; ++i) {
                int grow = rbase + i;
                if (grow >= mend) continue;
                EO[(long)grow * HDIM + col] = f2bf(acc[m][n][i]);
            }
        }
    }
}

// ---------------- combine: out = w0*eo[r0] + w1*eo[r1] + eo[sh0] + eo[sh1] ----------------
__global__ __launch_bounds__(256) void combine_k(float* __restrict__ out,
                                                 const u16* __restrict__ eo,
                                                 const int* __restrict__ invmap,
                                                 const float* __restrict__ wts) {
    int t = blockIdx.x;
    int h = threadIdx.x * 4;
    int r0 = invmap[t * 2], r1 = invmap[t * 2 + 1];
    float w0 = wts[t * 2], w1 = wts[t * 2 + 1];
    int s0 = 8192 + t, s1 = 8192 + T_TOK + t;
    ushort4 a = *(const ushort4*)(eo + (long)r0 * HDIM + h);
    ushort4 b = *(const ushort4*)(eo + (long)r1 * HDIM + h);
    ushort4 c = *(const ushort4*)(eo + (long)s0 * HDIM + h);
    ushort4 d = *(const ushort4*)(eo + (long)s1 * HDIM + h);
    float4 o;
    o.x = w0 * bf2f(a.x) + w1 * bf2f(b.x) + bf2f(c.x) + bf2f(d.x);
    o.y = w0 * bf2f(a.y) + w1 * bf2f(b.y) + bf2f(c.y) + bf2f(d.y);
    o.z = w0 * bf2f(a.z) + w1 * bf2f(b.z) + bf2f(c.z) + bf2f(d.z);
    o.w = w0 * bf2f(a.w) + w1 * bf2f(b.w) + bf2f(c.w) + bf2f(d.w);
    *(float4*)(out + (long)t * HDIM + h) = o;
}

extern "C" void kernel_launch(void* const* d_in, const int* in_sizes, int n_in,
                              void* d_out, int out_size, void* d_ws, size_t ws_size,
                              hipStream_t stream) {
    const float* x    = (const float*)d_in[0];
    const float* rw   = (const float*)d_in[1];
    const float* bias = (const float*)d_in[2];
    const float* wg   = (const float*)d_in[3];
    const float* wu   = (const float*)d_in[4];
    const float* wd   = (const float*)d_in[5];
    const float* swg  = (const float*)d_in[6];
    const float* swu  = (const float*)d_in[7];
    const float* swd  = (const float*)d_in[8];
    float* out = (float*)d_out;

    char* ws = (char*)d_ws;
    size_t o = 0;
    auto alloc = [&](size_t bytes) -> void* {
        void* p = ws + o;
        o += (bytes + 255) & ~(size_t)255;
        return p;
    };
    u16* x_bf = (u16*)alloc((size_t)T_TOK * HDIM * 2);
    u16* WtG  = (u16*)alloc((size_t)NEXP * IDIM * HDIM * 2);   // 16 MB
    u16* WtU  = (u16*)alloc((size_t)NEXP * IDIM * HDIM * 2);   // 16 MB (contiguous after WtG)
    u16* WtD  = (u16*)alloc((size_t)NEXP * HDIM * IDIM * 2);
    u16* SWtG = (u16*)alloc((size_t)2 * IDIM * HDIM * 2);
    u16* SWtU = (u16*)alloc((size_t)2 * IDIM * HDIM * 2);
    u16* SWtD = (u16*)alloc((size_t)2 * HDIM * IDIM * 2);
    u16* Hbuf = (u16*)alloc((size_t)NSLOT * IDIM * 2);         // 16 MB
    int*   sel     = (int*)alloc((size_t)T_TOK * 2 * 4);
    float* wts     = (float*)alloc((size_t)T_TOK * 2 * 4);
    int*   invmap  = (int*)alloc((size_t)T_TOK * 2 * 4);
    int*   rowmap  = (int*)alloc((size_t)NSLOT * 4);
    int*   offs    = (int*)alloc((NGRP + 1) * 4);
    int*   rbGroup = (int*)alloc(MAXRB * 4);
    int*   rbRow0  = (int*)alloc(MAXRB * 4);
    // EO (32 MB) aliases WtG+WtU, which are dead after gemm_gu completes.
    u16* EO = WtG;

    cvt_f32_bf16<<<dim3((T_TOK * HDIM) / (4 * 256)), 256, 0, stream>>>(x, x_bf, T_TOK * HDIM);

    // routed weights -> bf16, [N][K] layouts
    transpose_k<<<dim3(IDIM / 32, HDIM / 32, NEXP), dim3(32, 8), 0, stream>>>(wg, WtG, HDIM, IDIM, (long)HDIM * IDIM);
    transpose_k<<<dim3(IDIM / 32, HDIM / 32, NEXP), dim3(32, 8), 0, stream>>>(wu, WtU, HDIM, IDIM, (long)HDIM * IDIM);
    transpose_k<<<dim3(HDIM / 32, IDIM / 32, NEXP), dim3(32, 8), 0, stream>>>(wd, WtD, IDIM, HDIM, (long)IDIM * HDIM);
    // shared weights as 2 pseudo-experts
    transpose_k<<<dim3(32, 32, 1), dim3(32, 8), 0, stream>>>(swg, SWtG, HDIM, 2 * IDIM, 0);
    transpose_k<<<dim3(32, 32, 1), dim3(32, 8), 0, stream>>>(swu, SWtU, HDIM, 2 * IDIM, 0);
    transpose_k<<<dim3(HDIM / 32, IDIM / 32, 2), dim3(32, 8), 0, stream>>>(swd, SWtD, IDIM, HDIM, (long)IDIM * HDIM);

    router_k<<<dim3(T_TOK / 4), 256, 0, stream>>>(x, rw, bias, sel, wts);
    route_build_k<<<dim3(1), 1024, 0, stream>>>(sel, offs, rowmap, invmap, rbGroup, rbRow0);

    gemm_gu<<<dim3(IDIM / 64, MAXRB), 256, 0, stream>>>(
        x_bf, WtG, WtU, SWtG, SWtU, Hbuf, offs, rowmap, rbGroup, rbRow0);

    gemm_down<<<dim3(HDIM / 128, MAXRB), 256, 0, stream>>>(
        Hbuf, WtD, SWtD, EO, offs, rbGroup, rbRow0);

    combine_k<<<dim3(T_TOK), 256, 0, stream>>>(out, EO, invmap, wts);
}

// Round 6
// 175.671 us; speedup vs baseline: 2.3571x; 1.0019x over previous
//
#include <hip/hip_runtime.h>
#include <math.h>

#define T_TOK 4096
#define HDIM  1024
#define NEXP  16
#define IDIM  512
#define NSLOT 16384          // 8192 routed + 2*4096 shared-pseudo
#define NGRP  18
#define MAXRB 160

typedef unsigned int u32;
typedef unsigned short u16;
typedef __attribute__((ext_vector_type(8))) short bfrag;   // 8 bf16 (4 VGPRs)
typedef __attribute__((ext_vector_type(4))) float f32x4;

__device__ __forceinline__ u16 f2bf(float f) {
    union { float f; u32 u; } c; c.f = f;
    u32 u = c.u;
    u32 r = u + 0x7fffu + ((u >> 16) & 1u);   // RNE
    return (u16)(r >> 16);
}
__device__ __forceinline__ float bf2f(u16 h) {
    union { u32 u; float f; } c; c.u = ((u32)h) << 16;
    return c.f;
}

__device__ __forceinline__ void async16(void* lds, const void* g) {
    __builtin_amdgcn_global_load_lds((__attribute__((address_space(1))) void*)(g),
                                     (__attribute__((address_space(3))) void*)(lds),
                                     16, 0, 0);
}

// counted-wait + raw barrier (never drain vmcnt to 0 inside the K-loop)
#define SYNCN(n) do { \
    asm volatile("s_waitcnt vmcnt(" #n ")" ::: "memory"); \
    __builtin_amdgcn_s_barrier(); \
    __builtin_amdgcn_sched_barrier(0); \
} while (0)
#define BAR2() do { \
    __builtin_amdgcn_s_barrier(); \
    __builtin_amdgcn_sched_barrier(0); \
} while (0)

// ---------------- f32 -> bf16 convert (x) ----------------
__global__ __launch_bounds__(256) void cvt_f32_bf16(const float* __restrict__ src,
                                                    u16* __restrict__ dst, int n) {
    int i = (blockIdx.x * 256 + threadIdx.x) * 4;
    if (i >= n) return;
    float4 v = *(const float4*)(src + i);
    ushort4 o;
    o.x = f2bf(v.x); o.y = f2bf(v.y); o.z = f2bf(v.z); o.w = f2bf(v.w);
    *(ushort4*)(dst + i) = o;
}

// ---------------- transpose f32 [R][C] -> bf16 [C][R], batched ----------------
__global__ __launch_bounds__(256) void transpose_k(const float* __restrict__ src,
                                                   u16* __restrict__ dst,
                                                   int R, int C, long bstride) {
    __shared__ float tile[32][33];
    long base = (long)blockIdx.z * bstride;
    int c0 = blockIdx.x * 32, r0 = blockIdx.y * 32;
    int tx = threadIdx.x, ty = threadIdx.y;   // (32, 8)
#pragma unroll
    for (int j = 0; j < 4; ++j)
        tile[ty + 8 * j][tx] = src[base + (long)(r0 + ty + 8 * j) * C + (c0 + tx)];
    __syncthreads();
#pragma unroll
    for (int j = 0; j < 4; ++j)
        dst[base + (long)(c0 + ty + 8 * j) * R + (r0 + tx)] = f2bf(tile[tx][ty + 8 * j]);
}

// ---------------- router: one wave per token, no global atomics ----------------
__global__ __launch_bounds__(256) void router_k(const float* __restrict__ x,
                                                const float* __restrict__ rw,
                                                const float* __restrict__ bias,
                                                int* __restrict__ sel,
                                                float* __restrict__ wts) {
    int tid = threadIdx.x;
    int wv = tid >> 6;
    int lane = tid & 63;
    int t = blockIdx.x * 4 + wv;
    int e = lane & 15, hc = lane >> 4;
    const float* xr = x + (long)t * HDIM + hc * 256;
    const float* rp = rw + (long)hc * 256 * NEXP + e;
    float acc = 0.f;
#pragma unroll 4
    for (int i = 0; i < 64; ++i) {
        float4 xv = *(const float4*)(xr + i * 4);
        acc += xv.x * rp[(i * 4 + 0) * NEXP] + xv.y * rp[(i * 4 + 1) * NEXP]
             + xv.z * rp[(i * 4 + 2) * NEXP] + xv.w * rp[(i * 4 + 3) * NEXP];
    }
    acc += __shfl_down(acc, 16);
    acc += __shfl_down(acc, 32);
    float sc = 1.f / (1.f + __expf(-acc));     // valid on lanes 0..15
    float v = sc + bias[e];
    int i0 = -1, i1 = -1;
    float v0 = -1e30f, v1 = -1e30f, s0 = 0.f, s1 = 0.f;
#pragma unroll
    for (int j = 0; j < 16; ++j) {
        float vj = __shfl(v, j);
        float scj = __shfl(sc, j);
        if (vj > v0) { v1 = v0; i1 = i0; s1 = s0; v0 = vj; i0 = j; s0 = scj; }
        else if (vj > v1) { v1 = vj; i1 = j; s1 = scj; }
    }
    if (lane == 0) {
        float nrm = s0 + s1 + 1e-20f;
        sel[t * 2] = i0; sel[t * 2 + 1] = i1;
        wts[t * 2] = s0 / nrm; wts[t * 2 + 1] = s1 / nrm;
    }
}

// ---------------- routing build: single block, LDS atomics only ----------------
__global__ __launch_bounds__(1024) void route_build_k(const int* __restrict__ sel,
                                                      int* __restrict__ offs,
                                                      int* __restrict__ rowmap,
                                                      int* __restrict__ invmap,
                                                      int* __restrict__ rbGroup,
                                                      int* __restrict__ rbRow0) {
    __shared__ int hist[NEXP];
    __shared__ int cur[NEXP];
    int tid = threadIdx.x;
    if (tid < NEXP) hist[tid] = 0;
    __syncthreads();
    for (int i = tid; i < T_TOK * 2; i += 1024)
        atomicAdd(&hist[sel[i]], 1);
    __syncthreads();
    if (tid == 0) {
        int a = 0;
        for (int g = 0; g < NEXP; ++g) { cur[g] = a; offs[g] = a; a += hist[g]; }
        offs[16] = 8192;
        offs[17] = 8192 + T_TOK;
        offs[18] = 8192 + 2 * T_TOK;
        int rb = 0;
        for (int g = 0; g < NGRP; ++g)
            for (int r0 = offs[g]; r0 < offs[g + 1]; r0 += 128) {
                rbGroup[rb] = g; rbRow0[rb] = r0; ++rb;
            }
        for (; rb < MAXRB; ++rb) rbGroup[rb] = -1;
    }
    __syncthreads();
    for (int i = tid; i < T_TOK * 2; i += 1024) {
        int g = sel[i];
        int slot = atomicAdd(&cur[g], 1);
        rowmap[slot] = i >> 1;
        invmap[i] = slot;
    }
    for (int i = tid; i < T_TOK; i += 1024) {
        rowmap[8192 + i] = i;
        rowmap[8192 + T_TOK + i] = i;
    }
}

// ---------------- grouped fused gate+up GEMM, prefetch double-buffer ----------------
// 128-row x 64-col tile; K = HDIM, NT = 16 K-steps. H[slot][I] = silu(g)*u bf16.
// Chunk-XOR swizzled LDS (source-side + read-side involution); counted vmcnt.
__global__ __launch_bounds__(256)
void gemm_gu(const u16* __restrict__ A,            // x_bf [T][H]
             const u16* __restrict__ WG,           // [16][512][1024]
             const u16* __restrict__ WU,
             const u16* __restrict__ SWG,          // [2*512][1024]
             const u16* __restrict__ SWU,
             u16* __restrict__ H,                  // [NSLOT][512]
             const int* __restrict__ offs,
             const int* __restrict__ rowmap,
             const int* __restrict__ rbGroup,
             const int* __restrict__ rbRow0) {
    int rb = blockIdx.y;
    int g = rbGroup[rb];
    if (g < 0) return;
    int row0 = rbRow0[rb];
    int mend = offs[g + 1];
    int col0 = blockIdx.x * 64;
    long wb = (long)((g < 16) ? g : (g - 16)) * IDIM * HDIM;
    const u16* Bg = (g < 16) ? WG + wb : SWG + wb;
    const u16* Bu = (g < 16) ? WU + wb : SWU + wb;

    __shared__ u16 sA[2][128 * 64];
    __shared__ u16 sBg[2][64 * 64];
    __shared__ u16 sBu[2][64 * 64];

    int tid = threadIdx.x;
    int lane = tid & 63;
    int w = tid >> 6;
    int wr = (w >> 1) * 64, wc = (w & 1) * 32;
    int lhi = lane >> 4, llo = lane & 15;
    int swz = llo & 7;

    // hoisted staging pointers (swizzled global source, linear LDS dest)
    const u16* pA[4]; int dA[4];
#pragma unroll
    for (int c = 0; c < 4; ++c) {
        int idx = c * 256 + tid;
        int r = idx >> 3, ch = idx & 7;
        int grow = row0 + r;
        int ar = rowmap[(grow < mend) ? grow : row0];
        pA[c] = A + (long)ar * HDIM + ((ch ^ (r & 7)) * 8);
        dA[c] = idx * 8;
    }
    const u16* pBg[2]; const u16* pBu[2]; int dB[2];
#pragma unroll
    for (int c = 0; c < 2; ++c) {
        int idx = c * 256 + tid;
        int r = idx >> 3, ch = idx & 7;
        long boff = (long)(col0 + r) * HDIM + ((ch ^ (r & 7)) * 8);
        pBg[c] = Bg + boff; pBu[c] = Bu + boff;
        dB[c] = idx * 8;
    }

    f32x4 accg[4][2], accu[4][2];
#pragma unroll
    for (int m = 0; m < 4; ++m)
#pragma unroll
        for (int n = 0; n < 2; ++n) {
            f32x4 z = {0.f, 0.f, 0.f, 0.f};
            accg[m][n] = z; accu[m][n] = z;
        }

    auto STAGE = [&](int buf) {
#pragma unroll
        for (int c = 0; c < 4; ++c) { async16(&sA[buf][dA[c]], pA[c]); pA[c] += 64; }
#pragma unroll
        for (int c = 0; c < 2; ++c) {
            async16(&sBg[buf][dB[c]], pBg[c]); pBg[c] += 64;
            async16(&sBu[buf][dB[c]], pBu[c]); pBu[c] += 64;
        }
    };
    auto COMPUTE = [&](int buf) {
#pragma unroll
        for (int kk = 0; kk < 2; ++kk) {
            int p = ((kk * 4 + lhi) ^ swz) * 8;   // swizzled chunk position
            bfrag a[4], bg[2], bu[2];
#pragma unroll
            for (int m = 0; m < 4; ++m)
                a[m] = *(const bfrag*)&sA[buf][(wr + m * 16 + llo) * 64 + p];
#pragma unroll
            for (int n = 0; n < 2; ++n) {
                bg[n] = *(const bfrag*)&sBg[buf][(wc + n * 16 + llo) * 64 + p];
                bu[n] = *(const bfrag*)&sBu[buf][(wc + n * 16 + llo) * 64 + p];
            }
#pragma unroll
            for (int m = 0; m < 4; ++m)
#pragma unroll
                for (int n = 0; n < 2; ++n) {
                    accg[m][n] = __builtin_amdgcn_mfma_f32_16x16x32_bf16(a[m], bg[n], accg[m][n], 0, 0, 0);
                    accu[m][n] = __builtin_amdgcn_mfma_f32_16x16x32_bf16(a[m], bu[n], accu[m][n], 0, 0, 0);
                }
        }
    };

    // NT = 16: prologue + 7x unrolled-pair + tail pair
    STAGE(0);
#pragma unroll 1
    for (int t = 0; t < 14; t += 2) {
        STAGE(1); SYNCN(8); COMPUTE(0); BAR2();
        STAGE(0); SYNCN(8); COMPUTE(1); BAR2();
    }
    STAGE(1); SYNCN(8); COMPUTE(0); BAR2();
    SYNCN(0); COMPUTE(1);

#pragma unroll
    for (int m = 0; m < 4; ++m) {
        int rbase = row0 + wr + m * 16 + lhi * 4;
#pragma unroll
        for (int n = 0; n < 2; ++n) {
            int col = col0 + wc + n * 16 + llo;
#pragma unroll
            for (int i = 0; i < 4; ++i) {
                int grow = rbase + i;
                if (grow >= mend) continue;
                float gv = accg[m][n][i], uv = accu[m][n][i];
                float hv = gv / (1.f + __expf(-gv)) * uv;
                H[(long)grow * IDIM + col] = f2bf(hv);
            }
        }
    }
}

// ---------------- grouped down GEMM, prefetch double-buffer ----------------
// NT = IDIM/64 = 8 K-steps.
__global__ __launch_bounds__(256)
void gemm_down(const u16* __restrict__ Hbuf,       // [NSLOT][512]
               const u16* __restrict__ WD,         // [16][1024][512]
               const u16* __restrict__ SWD,        // [2][1024][512]
               u16* __restrict__ EO,               // [NSLOT][1024]
               const int* __restrict__ offs,
               const int* __restrict__ rbGroup,
               const int* __restrict__ rbRow0) {
    int rb = blockIdx.y;
    int g = rbGroup[rb];
    if (g < 0) return;
    int row0 = rbRow0[rb];
    int mend = offs[g + 1];
    int col0 = blockIdx.x * 128;
    long wb = (long)((g < 16) ? g : (g - 16)) * HDIM * IDIM;
    const u16* B = (g < 16) ? WD + wb : SWD + wb;

    __shared__ u16 sA[2][128 * 64];
    __shared__ u16 sB[2][128 * 64];

    int tid = threadIdx.x;
    int lane = tid & 63;
    int w = tid >> 6;
    int wr = (w >> 1) * 64, wc = (w & 1) * 64;
    int lhi = lane >> 4, llo = lane & 15;
    int swz = llo & 7;

    const u16* pA[4]; const u16* pB[4]; int dd[4];
#pragma unroll
    for (int c = 0; c < 4; ++c) {
        int idx = c * 256 + tid;
        int r = idx >> 3, ch = idx & 7;
        int grow = row0 + r;
        int ar = (grow < mend) ? grow : row0;
        int chs = (ch ^ (r & 7)) * 8;
        pA[c] = Hbuf + (long)ar * IDIM + chs;
        pB[c] = B + (long)(col0 + r) * IDIM + chs;
        dd[c] = idx * 8;
    }

    f32x4 acc[4][4];
#pragma unroll
    for (int m = 0; m < 4; ++m)
#pragma unroll
        for (int n = 0; n < 4; ++n) { f32x4 z = {0.f, 0.f, 0.f, 0.f}; acc[m][n] = z; }

    auto STAGE = [&](int buf) {
#pragma unroll
        for (int c = 0; c < 4; ++c) {
            async16(&sA[buf][dd[c]], pA[c]); pA[c] += 64;
            async16(&sB[buf][dd[c]], pB[c]); pB[c] += 64;
        }
    };
    auto COMPUTE = [&](int buf) {
#pragma unroll
        for (int kk = 0; kk < 2; ++kk) {
            int p = ((kk * 4 + lhi) ^ swz) * 8;
            bfrag a[4], b[4];
#pragma unroll
            for (int m = 0; m < 4; ++m)
                a[m] = *(const bfrag*)&sA[buf][(wr + m * 16 + llo) * 64 + p];
#pragma unroll
            for (int n = 0; n < 4; ++n)
                b[n] = *(const bfrag*)&sB[buf][(wc + n * 16 + llo) * 64 + p];
#pragma unroll
            for (int m = 0; m < 4; ++m)
#pragma unroll
                for (int n = 0; n < 4; ++n)
                    acc[m][n] = __builtin_amdgcn_mfma_f32_16x16x32_bf16(a[m], b[n], acc[m][n], 0, 0, 0);
        }
    };

    // NT = 8: prologue + 3x pair + tail pair
    STAGE(0);
#pragma unroll 1
    for (int t = 0; t < 6; t += 2) {
        STAGE(1); SYNCN(8); COMPUTE(0); BAR2();
        STAGE(0); SYNCN(8); COMPUTE(1); BAR2();
    }
    STAGE(1); SYNCN(8); COMPUTE(0); BAR2();
    SYNCN(0); COMPUTE(1);

#pragma unroll
    for (int m = 0; m < 4; ++m) {
        int rbase = row0 + wr + m * 16 + lhi * 4;
#pragma unroll
        for (int n = 0; n < 4; ++n) {
            int col = col0 + wc + n * 16 + llo;
#pragma unroll
            for (int i = 0; i < 4; ++i) {
                int grow = rbase + i;
                if (grow >= mend) continue;
                EO[(long)grow * HDIM + col] = f2bf(acc[m][n][i]);
            }
        }
    }
}

// ---------------- combine: out = w0*eo[r0] + w1*eo[r1] + eo[sh0] + eo[sh1] ----------------
__global__ __launch_bounds__(256) void combine_k(float* __restrict__ out,
                                                 const u16* __restrict__ eo,
                                                 const int* __restrict__ invmap,
                                                 const float* __restrict__ wts) {
    int t = blockIdx.x;
    int h = threadIdx.x * 4;
    int r0 = invmap[t * 2], r1 = invmap[t * 2 + 1];
    float w0 = wts[t * 2], w1 = wts[t * 2 + 1];
    int s0 = 8192 + t, s1 = 8192 + T_TOK + t;
    ushort4 a = *(const ushort4*)(eo + (long)r0 * HDIM + h);
    ushort4 b = *(const ushort4*)(eo + (long)r1 * HDIM + h);
    ushort4 c = *(const ushort4*)(eo + (long)s0 * HDIM + h);
    ushort4 d = *(const ushort4*)(eo + (long)s1 * HDIM + h);
    float4 o;
    o.x = w0 * bf2f(a.x) + w1 * bf2f(b.x) + bf2f(c.x) + bf2f(d.x);
    o.y = w0 * bf2f(a.y) + w1 * bf2f(b.y) + bf2f(c.y) + bf2f(d.y);
    o.z = w0 * bf2f(a.z) + w1 * bf2f(b.z) + bf2f(c.z) + bf2f(d.z);
    o.w = w0 * bf2f(a.w) + w1 * bf2f(b.w) + bf2f(c.w) + bf2f(d.w);
    *(float4*)(out + (long)t * HDIM + h) = o;
}

extern "C" void kernel_launch(void* const* d_in, const int* in_sizes, int n_in,
                              void* d_out, int out_size, void* d_ws, size_t ws_size,
                              hipStream_t stream) {
    const float* x    = (const float*)d_in[0];
    const float* rw   = (const float*)d_in[1];
    const float* bias = (const float*)d_in[2];
    const float* wg   = (const float*)d_in[3];
    const float* wu   = (const float*)d_in[4];
    const float* wd   = (const float*)d_in[5];
    const float* swg  = (const float*)d_in[6];
    const float* swu  = (const float*)d_in[7];
    const float* swd  = (const float*)d_in[8];
    float* out = (float*)d_out;

    char* ws = (char*)d_ws;
    size_t o = 0;
    auto alloc = [&](size_t bytes) -> void* {
        void* p = ws + o;
        o += (bytes + 255) & ~(size_t)255;
        return p;
    };
    u16* x_bf = (u16*)alloc((size_t)T_TOK * HDIM * 2);
    u16* WtG  = (u16*)alloc((size_t)NEXP * IDIM * HDIM * 2);   // 16 MB
    u16* WtU  = (u16*)alloc((size_t)NEXP * IDIM * HDIM * 2);   // 16 MB (contiguous after WtG)
    u16* WtD  = (u16*)alloc((size_t)NEXP * HDIM * IDIM * 2);
    u16* SWtG = (u16*)alloc((size_t)2 * IDIM * HDIM * 2);
    u16* SWtU = (u16*)alloc((size_t)2 * IDIM * HDIM * 2);
    u16* SWtD = (u16*)alloc((size_t)2 * HDIM * IDIM * 2);
    u16* Hbuf = (u16*)alloc((size_t)NSLOT * IDIM * 2);         // 16 MB
    int*   sel     = (int*)alloc((size_t)T_TOK * 2 * 4);
    float* wts     = (float*)alloc((size_t)T_TOK * 2 * 4);
    int*   invmap  = (int*)alloc((size_t)T_TOK * 2 * 4);
    int*   rowmap  = (int*)alloc((size_t)NSLOT * 4);
    int*   offs    = (int*)alloc((NGRP + 1) * 4);
    int*   rbGroup = (int*)alloc(MAXRB * 4);
    int*   rbRow0  = (int*)alloc(MAXRB * 4);
    // EO (32 MB) aliases WtG+WtU, which are dead after gemm_gu completes.
    u16* EO = WtG;

    cvt_f32_bf16<<<dim3((T_TOK * HDIM) / (4 * 256)), 256, 0, stream>>>(x, x_bf, T_TOK * HDIM);

    // routed weights -> bf16, [N][K] layouts
    transpose_k<<<dim3(IDIM / 32, HDIM / 32, NEXP), dim3(32, 8), 0, stream>>>(wg, WtG, HDIM, IDIM, (long)HDIM * IDIM);
    transpose_k<<<dim3(IDIM / 32, HDIM / 32, NEXP), dim3(32, 8), 0, stream>>>(wu, WtU, HDIM, IDIM, (long)HDIM * IDIM);
    transpose_k<<<dim3(HDIM / 32, IDIM / 32, NEXP), dim3(32, 8), 0, stream>>>(wd, WtD, IDIM, HDIM, (long)IDIM * HDIM);
    // shared weights as 2 pseudo-experts
    transpose_k<<<dim3(32, 32, 1), dim3(32, 8), 0, stream>>>(swg, SWtG, HDIM, 2 * IDIM, 0);
    transpose_k<<<dim3(32, 32, 1), dim3(32, 8), 0, stream>>>(swu, SWtU, HDIM, 2 * IDIM, 0);
    transpose_k<<<dim3(HDIM / 32, IDIM / 32, 2), dim3(32, 8), 0, stream>>>(swd, SWtD, IDIM, HDIM, (long)IDIM * HDIM);

    router_k<<<dim3(T_TOK / 4), 256, 0, stream>>>(x, rw, bias, sel, wts);
    route_build_k<<<dim3(1), 1024, 0, stream>>>(sel, offs, rowmap, invmap, rbGroup, rbRow0);

    gemm_gu<<<dim3(IDIM / 64, MAXRB), 256, 0, stream>>>(
        x_bf, WtG, WtU, SWtG, SWtU, Hbuf, offs, rowmap, rbGroup, rbRow0);

    gemm_down<<<dim3(HDIM / 128, MAXRB), 256, 0, stream>>>(
        Hbuf, WtD, SWtD, EO, offs, rbGroup, rbRow0);

    combine_k<<<dim3(T_TOK), 256, 0, stream>>>(out, EO, invmap, wts);
}